// Round 5
// baseline (296.530 us; speedup 1.0000x reference)
//
#include <hip/hip_runtime.h>
#include <hip/hip_bf16.h>

// ---------------------------------------------------------------------------
// GAT 2-layer forward on MI355X.
//   CSR build via atomic-free counting sort (LDS histograms + scans).
//   GEMMs via bf16 MFMA 16x16x32, **LDS-free / barrier-free**: lanes load
//   A/B fragments directly from global (A-frag = 8 contiguous k-elems per
//   lane), 16 loads in flight per lane hide HBM latency without occupancy.
//   h1/helu/h2 stored bf16 (half gather bytes in attention).
//   Single-pass softmax-aggregation (logits bounded), unroll-4 edge loop.
// ---------------------------------------------------------------------------

typedef __attribute__((ext_vector_type(8))) short short8;
typedef __attribute__((ext_vector_type(4))) float f4;

#define NCHUNK 64      // edge chunks
#define NRANGE 4       // node ranges
#define RSIZE 16384    // nodes per range (64 KB LDS histogram)

__device__ __forceinline__ unsigned short f2bf(float f) {
  unsigned int u = __builtin_bit_cast(unsigned int, f);
  u += 0x7fffu + ((u >> 16) & 1u);             // round-nearest-even
  return (unsigned short)(u >> 16);
}
__device__ __forceinline__ float bf2f(unsigned short h) {
  unsigned int u = ((unsigned int)h) << 16;
  return __builtin_bit_cast(float, u);
}

// ------------------------- CSR build (atomic-free) -------------------------
__global__ __launch_bounds__(512) void hist_kernel(const int* __restrict__ ei,
                                                   int* __restrict__ hist,
                                                   int E, int N, int ET, int CS) {
  __shared__ int lh[RSIZE];
  const int c = blockIdx.x & (NCHUNK - 1);
  const int r = blockIdx.x >> 6;
  const int base = r * RSIZE;
  for (int i = threadIdx.x; i < RSIZE; i += 512) lh[i] = 0;
  __syncthreads();
  const int e0 = c * CS, e1 = min(e0 + CS, ET);
  for (int e = e0 + threadIdx.x; e < e1; e += 512) {
    int d = (e < E) ? ei[E + e] : (e - E);
    unsigned dl = (unsigned)(d - base);
    if (dl < RSIZE) atomicAdd(&lh[dl], 1);
  }
  __syncthreads();
  for (int i = threadIdx.x; i < RSIZE; i += 512) {
    int d = base + i;
    if (d < N) hist[c * N + d] = lh[i];
  }
}

__global__ __launch_bounds__(256) void colscan_kernel(int* __restrict__ hist,
                                                      int* __restrict__ deg, int N) {
  int d = blockIdx.x * 256 + threadIdx.x;
  if (d >= N) return;
  int run = 0;
#pragma unroll 8
  for (int c = 0; c < NCHUNK; ++c) {
    int v = hist[c * N + d];
    hist[c * N + d] = run;
    run += v;
  }
  deg[d] = run;
}

__global__ __launch_bounds__(1024) void scan1_kernel(const int* __restrict__ deg,
                                                     int* __restrict__ rowptr,
                                                     int* __restrict__ bsum, int N) {
  __shared__ int wtot[16];
  const int lane = threadIdx.x & 63, wid = threadIdx.x >> 6;
  int i = blockIdx.x * 1024 + threadIdx.x;
  int v = (i < N) ? deg[i] : 0;
  int incl = v;
#pragma unroll
  for (int off = 1; off < 64; off <<= 1) {
    int t = __shfl_up(incl, off, 64);
    if (lane >= off) incl += t;
  }
  if (lane == 63) wtot[wid] = incl;
  __syncthreads();
  int woff = 0;
#pragma unroll
  for (int w = 0; w < 16; ++w) woff += (w < wid) ? wtot[w] : 0;
  if (i < N) rowptr[i] = woff + incl - v;
  if (threadIdx.x == 1023) bsum[blockIdx.x] = woff + incl;
}

__global__ __launch_bounds__(64) void scan2_kernel(int* __restrict__ bsum, int NB) {
  int lane = threadIdx.x;
  int v = (lane < NB) ? bsum[lane] : 0;
  int incl = v;
#pragma unroll
  for (int off = 1; off < 64; off <<= 1) {
    int t = __shfl_up(incl, off, 64);
    if (lane >= off) incl += t;
  }
  if (lane < NB) bsum[lane] = incl - v;
}

__global__ __launch_bounds__(256) void scan3_kernel(int* __restrict__ rowptr,
                                                    const int* __restrict__ bsum,
                                                    int N, int ET) {
  int i = blockIdx.x * 256 + threadIdx.x;
  if (i < N) rowptr[i] += bsum[i >> 10];
  if (i == N) rowptr[N] = ET;
}

__global__ __launch_bounds__(512) void scatter2_kernel(const int* __restrict__ ei,
                                                       const int* __restrict__ hist,
                                                       const int* __restrict__ rowptr,
                                                       int* __restrict__ csr_src,
                                                       int E, int N, int ET, int CS) {
  __shared__ int lh[RSIZE];
  const int c = blockIdx.x & (NCHUNK - 1);
  const int r = blockIdx.x >> 6;
  const int base = r * RSIZE;
  for (int i = threadIdx.x; i < RSIZE; i += 512) {
    int d = base + i;
    lh[i] = (d < N) ? (rowptr[d] + hist[c * N + d]) : 0;
  }
  __syncthreads();
  const int e0 = c * CS, e1 = min(e0 + CS, ET);
  for (int e = e0 + threadIdx.x; e < e1; e += 512) {
    int s, d;
    if (e < E) { s = ei[e]; d = ei[E + e]; }
    else       { s = e - E; d = s; }
    unsigned dl = (unsigned)(d - base);
    if (dl < RSIZE) {
      int slot = atomicAdd(&lh[dl], 1);
      csr_src[slot] = s;
    }
  }
}

// ------------------- weight transpose + bf16 convert ----------------------
__global__ __launch_bounds__(256) void convw_kernel(const float* __restrict__ W1,
                                                    const float* __restrict__ W2,
                                                    unsigned short* __restrict__ Wt1,
                                                    unsigned short* __restrict__ Wt2) {
  int i = blockIdx.x * blockDim.x + threadIdx.x;
  if (i < 128 * 256) {
    int n = i >> 8, k = i & 255;
    Wt1[i] = f2bf(W1[k * 128 + n]);
  } else {
    int j = i - 128 * 256;
    if (j < 64 * 128) {
      int n = j >> 7, k = j & 127;
      Wt2[j] = f2bf(W2[k * 64 + n]);
    }
  }
}

// ----------------------- GEMM1 (MFMA, LDS-free) ---------------------------
// H[M,128] = bf16( X[M,256] @ W1 ). Wave = 16 rows x 128 cols; A-fragment
// loaded directly from global (lane (m,q): X[r0+m][s*32+q*8..+8]); all 8
// K-step A-loads issued up-front. B from L2-resident Wt[n][k] (short8).
__global__ __launch_bounds__(256) void gemm1_direct(const float* __restrict__ X,
                                                    const unsigned short* __restrict__ Wt,
                                                    unsigned short* __restrict__ H,
                                                    int M) {
  const int t = threadIdx.x;
  const int wv = t >> 6, ln = t & 63;
  const int ml = ln & 15, q = ln >> 4;
  const int r0 = blockIdx.x * 64 + wv * 16;
  if (r0 >= M) return;
  const int arow = min(r0 + ml, M - 1);
  const float* xp = X + (size_t)arow * 256 + q * 8;

  float4 a0[8], a1[8];
#pragma unroll
  for (int s = 0; s < 8; ++s) {
    a0[s] = *(const float4*)(xp + s * 32);
    a1[s] = *(const float4*)(xp + s * 32 + 4);
  }

  f4 acc[8];
#pragma unroll
  for (int b = 0; b < 8; ++b) acc[b] = (f4)0.f;

  const unsigned short* wp = Wt + (size_t)ml * 256 + q * 8;
#pragma unroll
  for (int s = 0; s < 8; ++s) {
    short8 bfr[8];
#pragma unroll
    for (int b = 0; b < 8; ++b)
      bfr[b] = *(const short8*)(wp + (size_t)b * 16 * 256 + s * 32);
    short8 av;
    av[0] = (short)f2bf(a0[s].x); av[1] = (short)f2bf(a0[s].y);
    av[2] = (short)f2bf(a0[s].z); av[3] = (short)f2bf(a0[s].w);
    av[4] = (short)f2bf(a1[s].x); av[5] = (short)f2bf(a1[s].y);
    av[6] = (short)f2bf(a1[s].z); av[7] = (short)f2bf(a1[s].w);
#pragma unroll
    for (int b = 0; b < 8; ++b)
      acc[b] = __builtin_amdgcn_mfma_f32_16x16x32_bf16(av, bfr[b], acc[b], 0, 0, 0);
  }

#pragma unroll
  for (int i = 0; i < 4; ++i) {
    int rr = r0 + q * 4 + i;
    if (rr < M) {
#pragma unroll
      for (int b = 0; b < 8; ++b)
        H[(size_t)rr * 128 + b * 16 + ml] = f2bf(acc[b][i]);
    }
  }
}

// ----------------------- GEMM2 (MFMA, LDS-free) ---------------------------
// H[M,64] = bf16( helu[M,128](bf16) @ W2 ). Wave = 16 rows x 64 cols.
__global__ __launch_bounds__(256) void gemm2_direct(const unsigned short* __restrict__ Xb,
                                                    const unsigned short* __restrict__ Wt,
                                                    unsigned short* __restrict__ H,
                                                    int M) {
  const int t = threadIdx.x;
  const int wv = t >> 6, ln = t & 63;
  const int ml = ln & 15, q = ln >> 4;
  const int r0 = blockIdx.x * 64 + wv * 16;
  if (r0 >= M) return;
  const int arow = min(r0 + ml, M - 1);
  const unsigned short* xp = Xb + (size_t)arow * 128 + q * 8;

  short8 av[4];
#pragma unroll
  for (int s = 0; s < 4; ++s) av[s] = *(const short8*)(xp + s * 32);

  f4 acc[4];
#pragma unroll
  for (int b = 0; b < 4; ++b) acc[b] = (f4)0.f;

  const unsigned short* wp = Wt + (size_t)ml * 128 + q * 8;
#pragma unroll
  for (int s = 0; s < 4; ++s) {
    short8 bfr[4];
#pragma unroll
    for (int b = 0; b < 4; ++b)
      bfr[b] = *(const short8*)(wp + (size_t)b * 16 * 128 + s * 32);
#pragma unroll
    for (int b = 0; b < 4; ++b)
      acc[b] = __builtin_amdgcn_mfma_f32_16x16x32_bf16(av[s], bfr[b], acc[b], 0, 0, 0);
  }

#pragma unroll
  for (int i = 0; i < 4; ++i) {
    int rr = r0 + q * 4 + i;
    if (rr < M) {
#pragma unroll
      for (int b = 0; b < 4; ++b)
        H[(size_t)rr * 64 + b * 16 + ml] = f2bf(acc[b][i]);
    }
  }
}

// ------------------------------- dots -------------------------------------
__global__ __launch_bounds__(256) void dots1_kernel(const unsigned short* __restrict__ h1,
                                                    const float* __restrict__ as,
                                                    const float* __restrict__ ad,
                                                    float* __restrict__ als,
                                                    float* __restrict__ ald, int N) {
  int wave = (blockIdx.x * blockDim.x + threadIdx.x) >> 6;
  int lane = threadIdx.x & 63;
  if (wave >= N) return;
  float x0 = bf2f(h1[(size_t)wave * 128 + lane]);
  float x1 = bf2f(h1[(size_t)wave * 128 + 64 + lane]);
  float s0 = x0 * as[lane], s1 = x1 * as[64 + lane];
  float d0 = x0 * ad[lane], d1 = x1 * ad[64 + lane];
#pragma unroll
  for (int off = 8; off; off >>= 1) {
    s0 += __shfl_down(s0, off, 16); s1 += __shfl_down(s1, off, 16);
    d0 += __shfl_down(d0, off, 16); d1 += __shfl_down(d1, off, 16);
  }
  if ((lane & 15) == 0) {
    int h = lane >> 4;
    als[wave * 8 + h] = s0; als[wave * 8 + 4 + h] = s1;
    ald[wave * 8 + h] = d0; ald[wave * 8 + 4 + h] = d1;
  }
}

__global__ __launch_bounds__(256) void dots2_kernel(const unsigned short* __restrict__ h2,
                                                    const float* __restrict__ as,
                                                    const float* __restrict__ ad,
                                                    float* __restrict__ als,
                                                    float* __restrict__ ald, int N) {
  int wave = (blockIdx.x * blockDim.x + threadIdx.x) >> 6;
  int lane = threadIdx.x & 63;
  if (wave >= N) return;
  float x = bf2f(h2[(size_t)wave * 64 + lane]);
  float s = x * as[lane], d = x * ad[lane];
#pragma unroll
  for (int off = 32; off; off >>= 1) {
    s += __shfl_xor(s, off, 64);
    d += __shfl_xor(d, off, 64);
  }
  if (lane == 0) { als[wave] = s; ald[wave] = d; }
}

// ------------------------------- attn1 ------------------------------------
__global__ __launch_bounds__(256) void attn1_kernel(
    const unsigned short* __restrict__ h1, const float* __restrict__ als,
    const float* __restrict__ ald, const float* __restrict__ b1,
    const int* __restrict__ rowptr, const int* __restrict__ csr_src,
    unsigned short* __restrict__ helu, int N) {
  int d = __builtin_amdgcn_readfirstlane(
      (blockIdx.x * blockDim.x + threadIdx.x) >> 6);
  int lane = threadIdx.x & 63;
  if (d >= N) return;
  const int h = lane >> 3;
  const float aldd = ald[d * 8 + h];
  const int beg = rowptr[d], end = rowptr[d + 1];
  float den = 0.f;
  float ax = 0.f, ay = 0.f;
  int p = beg;
  for (; p + 4 <= end; p += 4) {
    int s0 = csr_src[p + 0], s1 = csr_src[p + 1];
    int s2 = csr_src[p + 2], s3 = csr_src[p + 3];
    float v0 = als[s0 * 8 + h] + aldd; v0 = v0 > 0.f ? v0 : 0.2f * v0;
    float v1 = als[s1 * 8 + h] + aldd; v1 = v1 > 0.f ? v1 : 0.2f * v1;
    float v2 = als[s2 * 8 + h] + aldd; v2 = v2 > 0.f ? v2 : 0.2f * v2;
    float v3 = als[s3 * 8 + h] + aldd; v3 = v3 > 0.f ? v3 : 0.2f * v3;
    float w0 = __expf(v0), w1 = __expf(v1), w2 = __expf(v2), w3 = __expf(v3);
    ushort2 g0 = *(const ushort2*)(h1 + (size_t)s0 * 128 + 2 * lane);
    ushort2 g1 = *(const ushort2*)(h1 + (size_t)s1 * 128 + 2 * lane);
    ushort2 g2 = *(const ushort2*)(h1 + (size_t)s2 * 128 + 2 * lane);
    ushort2 g3 = *(const ushort2*)(h1 + (size_t)s3 * 128 + 2 * lane);
    den += (w0 + w1) + (w2 + w3);
    ax += w0 * bf2f(g0.x) + w1 * bf2f(g1.x) + w2 * bf2f(g2.x) + w3 * bf2f(g3.x);
    ay += w0 * bf2f(g0.y) + w1 * bf2f(g1.y) + w2 * bf2f(g2.y) + w3 * bf2f(g3.y);
  }
  for (; p < end; ++p) {
    int s = csr_src[p];
    float v = als[s * 8 + h] + aldd; v = v > 0.f ? v : 0.2f * v;
    float w = __expf(v);
    ushort2 g = *(const ushort2*)(h1 + (size_t)s * 128 + 2 * lane);
    den += w;
    ax += w * bf2f(g.x); ay += w * bf2f(g.y);
  }
  float inv = 1.0f / (den + 1e-16f);
  float2 bb = *(const float2*)(b1 + 2 * lane);
  float o0 = ax * inv + bb.x;
  float o1 = ay * inv + bb.y;
  o0 = o0 > 0.f ? o0 : __expf(o0) - 1.0f;
  o1 = o1 > 0.f ? o1 : __expf(o1) - 1.0f;
  ushort2 ov; ov.x = f2bf(o0); ov.y = f2bf(o1);
  *(ushort2*)(helu + (size_t)d * 128 + 2 * lane) = ov;
}

// ------------------------------- attn2 ------------------------------------
__global__ __launch_bounds__(256) void attn2_kernel(
    const unsigned short* __restrict__ h2, const float* __restrict__ als,
    const float* __restrict__ ald, const float* __restrict__ b2,
    const int* __restrict__ rowptr, const int* __restrict__ csr_src,
    float* __restrict__ out, int N) {
  int d = __builtin_amdgcn_readfirstlane(
      (blockIdx.x * blockDim.x + threadIdx.x) >> 6);
  int lane = threadIdx.x & 63;
  if (d >= N) return;
  const float aldd = ald[d];
  const int beg = rowptr[d], end = rowptr[d + 1];
  float den = 0.f, acc = 0.f;
  int p = beg;
  for (; p + 4 <= end; p += 4) {
    int s0 = csr_src[p + 0], s1 = csr_src[p + 1];
    int s2 = csr_src[p + 2], s3 = csr_src[p + 3];
    float v0 = als[s0] + aldd; v0 = v0 > 0.f ? v0 : 0.2f * v0;
    float v1 = als[s1] + aldd; v1 = v1 > 0.f ? v1 : 0.2f * v1;
    float v2 = als[s2] + aldd; v2 = v2 > 0.f ? v2 : 0.2f * v2;
    float v3 = als[s3] + aldd; v3 = v3 > 0.f ? v3 : 0.2f * v3;
    float w0 = __expf(v0), w1 = __expf(v1), w2 = __expf(v2), w3 = __expf(v3);
    float g0 = bf2f(h2[(size_t)s0 * 64 + lane]);
    float g1 = bf2f(h2[(size_t)s1 * 64 + lane]);
    float g2 = bf2f(h2[(size_t)s2 * 64 + lane]);
    float g3 = bf2f(h2[(size_t)s3 * 64 + lane]);
    den += (w0 + w1) + (w2 + w3);
    acc += w0 * g0 + w1 * g1 + w2 * g2 + w3 * g3;
  }
  for (; p < end; ++p) {
    int s = csr_src[p];
    float v = als[s] + aldd; v = v > 0.f ? v : 0.2f * v;
    float w = __expf(v);
    den += w;
    acc += w * bf2f(h2[(size_t)s * 64 + lane]);
  }
  float z = acc / (den + 1e-16f) + b2[lane];
  float zm = z;
#pragma unroll
  for (int off = 32; off; off >>= 1) zm = fmaxf(zm, __shfl_xor(zm, off, 64));
  float ex = __expf(z - zm), se = ex;
#pragma unroll
  for (int off = 32; off; off >>= 1) se += __shfl_xor(se, off, 64);
  out[(size_t)d * 64 + lane] = z - zm - __logf(se);
}

// ------------------------------- launch -----------------------------------
extern "C" void kernel_launch(void* const* d_in, const int* in_sizes, int n_in,
                              void* d_out, int out_size, void* d_ws, size_t ws_size,
                              hipStream_t stream) {
  const int N = in_sizes[0] / 256;   // 50000
  const int E = in_sizes[1] / 2;     // 800000
  const int ET = E + N;
  const int CS = (ET + NCHUNK - 1) / NCHUNK;
  const int NB = (N + 1023) / 1024;

  const float* x   = (const float*)d_in[0];
  const int*   ei  = (const int*)d_in[1];
  const float* W1  = (const float*)d_in[2];
  const float* as1 = (const float*)d_in[3];
  const float* ad1 = (const float*)d_in[4];
  const float* b1  = (const float*)d_in[5];
  const float* W2  = (const float*)d_in[6];
  const float* as2 = (const float*)d_in[7];
  const float* ad2 = (const float*)d_in[8];
  const float* b2  = (const float*)d_in[9];
  float* out = (float*)d_out;

  // workspace carve. h2b aliases h1b (dead after attn1).
  // hist (NCHUNK*N ints) aliases helu (dead after scatter2 / written by attn1).
  char* p = (char*)d_ws;
  unsigned short* h1b  = (unsigned short*)p; p += (size_t)N * 128 * 2;
  unsigned short* h2b  = h1b;                       // alias, [N][64]
  unsigned short* helu = (unsigned short*)p; p += (size_t)NCHUNK * N * 4;  // shared w/ hist
  int* hist = (int*)helu;
  unsigned short* Wt1  = (unsigned short*)p; p += (size_t)128 * 256 * 2;
  unsigned short* Wt2  = (unsigned short*)p; p += (size_t)64 * 128 * 2;
  float* als1 = (float*)p; p += (size_t)N * 8 * 4;
  float* ald1 = (float*)p; p += (size_t)N * 8 * 4;
  float* als2 = (float*)p; p += (size_t)N * 4;
  float* ald2 = (float*)p; p += (size_t)N * 4;
  int* deg     = (int*)p; p += (size_t)N * 4;
  int* rowptr  = (int*)p; p += (size_t)(N + 1) * 4;
  int* bsum    = (int*)p; p += 64 * 4;
  int* csr_src = (int*)p; p += (size_t)ET * 4;

  convw_kernel<<<(128 * 256 + 64 * 128 + 255) / 256, 256, 0, stream>>>(W1, W2, Wt1, Wt2);

  hist_kernel<<<NCHUNK * NRANGE, 512, 0, stream>>>(ei, hist, E, N, ET, CS);
  colscan_kernel<<<(N + 255) / 256, 256, 0, stream>>>(hist, deg, N);
  scan1_kernel<<<NB, 1024, 0, stream>>>(deg, rowptr, bsum, N);
  scan2_kernel<<<1, 64, 0, stream>>>(bsum, NB);
  scan3_kernel<<<(N + 256) / 256, 256, 0, stream>>>(rowptr, bsum, N, ET);
  scatter2_kernel<<<NCHUNK * NRANGE, 512, 0, stream>>>(ei, hist, rowptr, csr_src, E, N, ET, CS);

  gemm1_direct<<<(N + 63) / 64, 256, 0, stream>>>(x, Wt1, h1b, N);
  dots1_kernel<<<(N + 3) / 4, 256, 0, stream>>>(h1b, as1, ad1, als1, ald1, N);
  attn1_kernel<<<(N + 3) / 4, 256, 0, stream>>>(h1b, als1, ald1, b1, rowptr, csr_src, helu, N);

  gemm2_direct<<<(N + 63) / 64, 256, 0, stream>>>(helu, Wt2, h2b, N);
  dots2_kernel<<<(N + 3) / 4, 256, 0, stream>>>(h2b, as2, ad2, als2, ald2, N);
  attn2_kernel<<<(N + 3) / 4, 256, 0, stream>>>(h2b, als2, ald2, b2, rowptr, csr_src, out, N);
}

// Round 6
// 273.479 us; speedup vs baseline: 1.0843x; 1.0843x over previous
//
#include <hip/hip_runtime.h>
#include <hip/hip_bf16.h>

// ---------------------------------------------------------------------------
// GAT 2-layer forward on MI355X.
//   CSR build via atomic-free counting sort (LDS histograms + scans).
//   GEMMs: bf16 MFMA 16x16x32. A-fragments direct from global with ALL
//   prefetches held in registers (launch_bounds min-waves raised so the
//   compiler actually keeps them live -- R5 failure was VGPR_Count=60
//   sinking the loads). B staged in LDS (K-halves, 3 barriers total).
//   h1/helu/h2 stored bf16 (half gather bytes in attention).
//   Single-pass softmax-aggregation (logits bounded), unroll-4 edge loop.
// ---------------------------------------------------------------------------

typedef __attribute__((ext_vector_type(8))) short short8;
typedef __attribute__((ext_vector_type(4))) float f4;

#define NCHUNK 64      // edge chunks
#define NRANGE 4       // node ranges
#define RSIZE 16384    // nodes per range (64 KB LDS histogram)
#define G1PAD 136      // LDS row stride (shorts) for B tiles: 68 dw = 4 mod 32
#define G2PAD 136

__device__ __forceinline__ unsigned short f2bf(float f) {
  unsigned int u = __builtin_bit_cast(unsigned int, f);
  u += 0x7fffu + ((u >> 16) & 1u);             // round-nearest-even
  return (unsigned short)(u >> 16);
}
__device__ __forceinline__ float bf2f(unsigned short h) {
  unsigned int u = ((unsigned int)h) << 16;
  return __builtin_bit_cast(float, u);
}

// ------------------------- CSR build (atomic-free) -------------------------
__global__ __launch_bounds__(512) void hist_kernel(const int* __restrict__ ei,
                                                   int* __restrict__ hist,
                                                   int E, int N, int ET, int CS) {
  __shared__ int lh[RSIZE];
  const int c = blockIdx.x & (NCHUNK - 1);
  const int r = blockIdx.x >> 6;
  const int base = r * RSIZE;
  for (int i = threadIdx.x; i < RSIZE; i += 512) lh[i] = 0;
  __syncthreads();
  const int e0 = c * CS, e1 = min(e0 + CS, ET);
  for (int e = e0 + threadIdx.x; e < e1; e += 512) {
    int d = (e < E) ? ei[E + e] : (e - E);
    unsigned dl = (unsigned)(d - base);
    if (dl < RSIZE) atomicAdd(&lh[dl], 1);
  }
  __syncthreads();
  for (int i = threadIdx.x; i < RSIZE; i += 512) {
    int d = base + i;
    if (d < N) hist[c * N + d] = lh[i];
  }
}

__global__ __launch_bounds__(256) void colscan_kernel(int* __restrict__ hist,
                                                      int* __restrict__ deg, int N) {
  int d = blockIdx.x * 256 + threadIdx.x;
  if (d >= N) return;
  int run = 0;
#pragma unroll 8
  for (int c = 0; c < NCHUNK; ++c) {
    int v = hist[c * N + d];
    hist[c * N + d] = run;
    run += v;
  }
  deg[d] = run;
}

__global__ __launch_bounds__(1024) void scan1_kernel(const int* __restrict__ deg,
                                                     int* __restrict__ rowptr,
                                                     int* __restrict__ bsum, int N) {
  __shared__ int wtot[16];
  const int lane = threadIdx.x & 63, wid = threadIdx.x >> 6;
  int i = blockIdx.x * 1024 + threadIdx.x;
  int v = (i < N) ? deg[i] : 0;
  int incl = v;
#pragma unroll
  for (int off = 1; off < 64; off <<= 1) {
    int t = __shfl_up(incl, off, 64);
    if (lane >= off) incl += t;
  }
  if (lane == 63) wtot[wid] = incl;
  __syncthreads();
  int woff = 0;
#pragma unroll
  for (int w = 0; w < 16; ++w) woff += (w < wid) ? wtot[w] : 0;
  if (i < N) rowptr[i] = woff + incl - v;
  if (threadIdx.x == 1023) bsum[blockIdx.x] = woff + incl;
}

__global__ __launch_bounds__(64) void scan2_kernel(int* __restrict__ bsum, int NB) {
  int lane = threadIdx.x;
  int v = (lane < NB) ? bsum[lane] : 0;
  int incl = v;
#pragma unroll
  for (int off = 1; off < 64; off <<= 1) {
    int t = __shfl_up(incl, off, 64);
    if (lane >= off) incl += t;
  }
  if (lane < NB) bsum[lane] = incl - v;
}

__global__ __launch_bounds__(256) void scan3_kernel(int* __restrict__ rowptr,
                                                    const int* __restrict__ bsum,
                                                    int N, int ET) {
  int i = blockIdx.x * 256 + threadIdx.x;
  if (i < N) rowptr[i] += bsum[i >> 10];
  if (i == N) rowptr[N] = ET;
}

__global__ __launch_bounds__(512) void scatter2_kernel(const int* __restrict__ ei,
                                                       const int* __restrict__ hist,
                                                       const int* __restrict__ rowptr,
                                                       int* __restrict__ csr_src,
                                                       int E, int N, int ET, int CS) {
  __shared__ int lh[RSIZE];
  const int c = blockIdx.x & (NCHUNK - 1);
  const int r = blockIdx.x >> 6;
  const int base = r * RSIZE;
  for (int i = threadIdx.x; i < RSIZE; i += 512) {
    int d = base + i;
    lh[i] = (d < N) ? (rowptr[d] + hist[c * N + d]) : 0;
  }
  __syncthreads();
  const int e0 = c * CS, e1 = min(e0 + CS, ET);
  for (int e = e0 + threadIdx.x; e < e1; e += 512) {
    int s, d;
    if (e < E) { s = ei[e]; d = ei[E + e]; }
    else       { s = e - E; d = s; }
    unsigned dl = (unsigned)(d - base);
    if (dl < RSIZE) {
      int slot = atomicAdd(&lh[dl], 1);
      csr_src[slot] = s;
    }
  }
}

// ------------------- weight transpose + bf16 convert ----------------------
__global__ __launch_bounds__(256) void convw_kernel(const float* __restrict__ W1,
                                                    const float* __restrict__ W2,
                                                    unsigned short* __restrict__ Wt1,
                                                    unsigned short* __restrict__ Wt2) {
  int i = blockIdx.x * blockDim.x + threadIdx.x;
  if (i < 128 * 256) {
    int n = i >> 8, k = i & 255;
    Wt1[i] = f2bf(W1[k * 128 + n]);
  } else {
    int j = i - 128 * 256;
    if (j < 64 * 128) {
      int n = j >> 7, k = j & 127;
      Wt2[j] = f2bf(W2[k * 64 + n]);
    }
  }
}

// ------------------------------ GEMM1 (MFMA) ------------------------------
// H[M,128] = bf16( X[M,256] @ W1 ). Wave = 16 rows x 128 cols. All 16 A
// prefetches live in registers (launch_bounds(256,3) -> ~170 VGPR budget).
// B staged in LDS in two K-halves; ds_read_b128 at LDS BW floor.
__global__ __launch_bounds__(256, 3) void gemm1_mfma(const float* __restrict__ X,
                                                     const unsigned short* __restrict__ Wt,
                                                     unsigned short* __restrict__ H,
                                                     int M) {
  __shared__ unsigned short bl[128 * G1PAD];
  const int t = threadIdx.x;
  const int wv = t >> 6, ln = t & 63;
  const int ml = ln & 15, q = ln >> 4;
  const int r0 = blockIdx.x * 64 + wv * 16;
  const int arow = min(r0 + ml, M - 1);
  const float* xp = X + (size_t)arow * 256 + q * 8;

  float4 a0[8], a1[8];
#pragma unroll
  for (int s = 0; s < 8; ++s) {
    a0[s] = *(const float4*)(xp + s * 32);
    a1[s] = *(const float4*)(xp + s * 32 + 4);
  }

  f4 acc[8];
#pragma unroll
  for (int b = 0; b < 8; ++b) acc[b] = (f4)0.f;

  const int crow = t >> 1, coff = (t & 1) * 64;
#pragma unroll
  for (int half = 0; half < 2; ++half) {
    __syncthreads();                       // prev-half reads done / first entry
    {
      const unsigned short* src = Wt + (size_t)crow * 256 + half * 128 + coff;
      unsigned short* dst = &bl[crow * G1PAD + coff];
#pragma unroll
      for (int c = 0; c < 8; ++c)
        *(short8*)(dst + c * 8) = *(const short8*)(src + c * 8);
    }
    __syncthreads();
#pragma unroll
    for (int sl = 0; sl < 4; ++sl) {
      const int s = half * 4 + sl;
      short8 av;
      av[0] = (short)f2bf(a0[s].x); av[1] = (short)f2bf(a0[s].y);
      av[2] = (short)f2bf(a0[s].z); av[3] = (short)f2bf(a0[s].w);
      av[4] = (short)f2bf(a1[s].x); av[5] = (short)f2bf(a1[s].y);
      av[6] = (short)f2bf(a1[s].z); av[7] = (short)f2bf(a1[s].w);
#pragma unroll
      for (int b = 0; b < 8; ++b) {
        short8 bfr = *(const short8*)&bl[(b * 16 + ml) * G1PAD + sl * 32 + q * 8];
        acc[b] = __builtin_amdgcn_mfma_f32_16x16x32_bf16(av, bfr, acc[b], 0, 0, 0);
      }
    }
  }

#pragma unroll
  for (int i = 0; i < 4; ++i) {
    int rr = r0 + q * 4 + i;
    if (rr < M) {
#pragma unroll
      for (int b = 0; b < 8; ++b)
        H[(size_t)rr * 128 + b * 16 + ml] = f2bf(acc[b][i]);
    }
  }
}

// ------------------------------ GEMM2 (MFMA) ------------------------------
// H[M,64] = bf16( helu[M,128](bf16) @ W2 ). Wave = 16 rows x 64 cols;
// B (16 KB) staged once in LDS.
__global__ __launch_bounds__(256, 4) void gemm2_mfma(const unsigned short* __restrict__ Xb,
                                                     const unsigned short* __restrict__ Wt,
                                                     unsigned short* __restrict__ H,
                                                     int M) {
  __shared__ unsigned short bl[64 * G2PAD];
  const int t = threadIdx.x;
  const int wv = t >> 6, ln = t & 63;
  const int ml = ln & 15, q = ln >> 4;
  const int r0 = blockIdx.x * 64 + wv * 16;
  const int arow = min(r0 + ml, M - 1);
  const unsigned short* xp = Xb + (size_t)arow * 128 + q * 8;

  short8 av[4];
#pragma unroll
  for (int s = 0; s < 4; ++s) av[s] = *(const short8*)(xp + s * 32);

  {
    const int crow = t >> 2, coff = (t & 3) * 32;
    const unsigned short* src = Wt + (size_t)crow * 128 + coff;
    unsigned short* dst = &bl[crow * G2PAD + coff];
#pragma unroll
    for (int c = 0; c < 4; ++c)
      *(short8*)(dst + c * 8) = *(const short8*)(src + c * 8);
  }
  __syncthreads();

  f4 acc[4];
#pragma unroll
  for (int b = 0; b < 4; ++b) acc[b] = (f4)0.f;

#pragma unroll
  for (int s = 0; s < 4; ++s) {
#pragma unroll
    for (int b = 0; b < 4; ++b) {
      short8 bfr = *(const short8*)&bl[(b * 16 + ml) * G2PAD + s * 32 + q * 8];
      acc[b] = __builtin_amdgcn_mfma_f32_16x16x32_bf16(av[s], bfr, acc[b], 0, 0, 0);
    }
  }

#pragma unroll
  for (int i = 0; i < 4; ++i) {
    int rr = r0 + q * 4 + i;
    if (rr < M) {
#pragma unroll
      for (int b = 0; b < 4; ++b)
        H[(size_t)rr * 64 + b * 16 + ml] = f2bf(acc[b][i]);
    }
  }
}

// ------------------------------- dots -------------------------------------
__global__ __launch_bounds__(256) void dots1_kernel(const unsigned short* __restrict__ h1,
                                                    const float* __restrict__ as,
                                                    const float* __restrict__ ad,
                                                    float* __restrict__ als,
                                                    float* __restrict__ ald, int N) {
  int wave = (blockIdx.x * blockDim.x + threadIdx.x) >> 6;
  int lane = threadIdx.x & 63;
  if (wave >= N) return;
  float x0 = bf2f(h1[(size_t)wave * 128 + lane]);
  float x1 = bf2f(h1[(size_t)wave * 128 + 64 + lane]);
  float s0 = x0 * as[lane], s1 = x1 * as[64 + lane];
  float d0 = x0 * ad[lane], d1 = x1 * ad[64 + lane];
#pragma unroll
  for (int off = 8; off; off >>= 1) {
    s0 += __shfl_down(s0, off, 16); s1 += __shfl_down(s1, off, 16);
    d0 += __shfl_down(d0, off, 16); d1 += __shfl_down(d1, off, 16);
  }
  if ((lane & 15) == 0) {
    int h = lane >> 4;
    als[wave * 8 + h] = s0; als[wave * 8 + 4 + h] = s1;
    ald[wave * 8 + h] = d0; ald[wave * 8 + 4 + h] = d1;
  }
}

__global__ __launch_bounds__(256) void dots2_kernel(const unsigned short* __restrict__ h2,
                                                    const float* __restrict__ as,
                                                    const float* __restrict__ ad,
                                                    float* __restrict__ als,
                                                    float* __restrict__ ald, int N) {
  int wave = (blockIdx.x * blockDim.x + threadIdx.x) >> 6;
  int lane = threadIdx.x & 63;
  if (wave >= N) return;
  float x = bf2f(h2[(size_t)wave * 64 + lane]);
  float s = x * as[lane], d = x * ad[lane];
#pragma unroll
  for (int off = 32; off; off >>= 1) {
    s += __shfl_xor(s, off, 64);
    d += __shfl_xor(d, off, 64);
  }
  if (lane == 0) { als[wave] = s; ald[wave] = d; }
}

// ------------------------------- attn1 ------------------------------------
__global__ __launch_bounds__(256) void attn1_kernel(
    const unsigned short* __restrict__ h1, const float* __restrict__ als,
    const float* __restrict__ ald, const float* __restrict__ b1,
    const int* __restrict__ rowptr, const int* __restrict__ csr_src,
    unsigned short* __restrict__ helu, int N) {
  int d = __builtin_amdgcn_readfirstlane(
      (blockIdx.x * blockDim.x + threadIdx.x) >> 6);
  int lane = threadIdx.x & 63;
  if (d >= N) return;
  const int h = lane >> 3;
  const float aldd = ald[d * 8 + h];
  const int beg = rowptr[d], end = rowptr[d + 1];
  float den = 0.f;
  float ax = 0.f, ay = 0.f;
  int p = beg;
  for (; p + 4 <= end; p += 4) {
    int s0 = csr_src[p + 0], s1 = csr_src[p + 1];
    int s2 = csr_src[p + 2], s3 = csr_src[p + 3];
    float v0 = als[s0 * 8 + h] + aldd; v0 = v0 > 0.f ? v0 : 0.2f * v0;
    float v1 = als[s1 * 8 + h] + aldd; v1 = v1 > 0.f ? v1 : 0.2f * v1;
    float v2 = als[s2 * 8 + h] + aldd; v2 = v2 > 0.f ? v2 : 0.2f * v2;
    float v3 = als[s3 * 8 + h] + aldd; v3 = v3 > 0.f ? v3 : 0.2f * v3;
    float w0 = __expf(v0), w1 = __expf(v1), w2 = __expf(v2), w3 = __expf(v3);
    ushort2 g0 = *(const ushort2*)(h1 + (size_t)s0 * 128 + 2 * lane);
    ushort2 g1 = *(const ushort2*)(h1 + (size_t)s1 * 128 + 2 * lane);
    ushort2 g2 = *(const ushort2*)(h1 + (size_t)s2 * 128 + 2 * lane);
    ushort2 g3 = *(const ushort2*)(h1 + (size_t)s3 * 128 + 2 * lane);
    den += (w0 + w1) + (w2 + w3);
    ax += w0 * bf2f(g0.x) + w1 * bf2f(g1.x) + w2 * bf2f(g2.x) + w3 * bf2f(g3.x);
    ay += w0 * bf2f(g0.y) + w1 * bf2f(g1.y) + w2 * bf2f(g2.y) + w3 * bf2f(g3.y);
  }
  for (; p < end; ++p) {
    int s = csr_src[p];
    float v = als[s * 8 + h] + aldd; v = v > 0.f ? v : 0.2f * v;
    float w = __expf(v);
    ushort2 g = *(const ushort2*)(h1 + (size_t)s * 128 + 2 * lane);
    den += w;
    ax += w * bf2f(g.x); ay += w * bf2f(g.y);
  }
  float inv = 1.0f / (den + 1e-16f);
  float2 bb = *(const float2*)(b1 + 2 * lane);
  float o0 = ax * inv + bb.x;
  float o1 = ay * inv + bb.y;
  o0 = o0 > 0.f ? o0 : __expf(o0) - 1.0f;
  o1 = o1 > 0.f ? o1 : __expf(o1) - 1.0f;
  ushort2 ov; ov.x = f2bf(o0); ov.y = f2bf(o1);
  *(ushort2*)(helu + (size_t)d * 128 + 2 * lane) = ov;
}

// ------------------------------- attn2 ------------------------------------
__global__ __launch_bounds__(256) void attn2_kernel(
    const unsigned short* __restrict__ h2, const float* __restrict__ als,
    const float* __restrict__ ald, const float* __restrict__ b2,
    const int* __restrict__ rowptr, const int* __restrict__ csr_src,
    float* __restrict__ out, int N) {
  int d = __builtin_amdgcn_readfirstlane(
      (blockIdx.x * blockDim.x + threadIdx.x) >> 6);
  int lane = threadIdx.x & 63;
  if (d >= N) return;
  const float aldd = ald[d];
  const int beg = rowptr[d], end = rowptr[d + 1];
  float den = 0.f, acc = 0.f;
  int p = beg;
  for (; p + 4 <= end; p += 4) {
    int s0 = csr_src[p + 0], s1 = csr_src[p + 1];
    int s2 = csr_src[p + 2], s3 = csr_src[p + 3];
    float v0 = als[s0] + aldd; v0 = v0 > 0.f ? v0 : 0.2f * v0;
    float v1 = als[s1] + aldd; v1 = v1 > 0.f ? v1 : 0.2f * v1;
    float v2 = als[s2] + aldd; v2 = v2 > 0.f ? v2 : 0.2f * v2;
    float v3 = als[s3] + aldd; v3 = v3 > 0.f ? v3 : 0.2f * v3;
    float w0 = __expf(v0), w1 = __expf(v1), w2 = __expf(v2), w3 = __expf(v3);
    float g0 = bf2f(h2[(size_t)s0 * 64 + lane]);
    float g1 = bf2f(h2[(size_t)s1 * 64 + lane]);
    float g2 = bf2f(h2[(size_t)s2 * 64 + lane]);
    float g3 = bf2f(h2[(size_t)s3 * 64 + lane]);
    den += (w0 + w1) + (w2 + w3);
    acc += w0 * g0 + w1 * g1 + w2 * g2 + w3 * g3;
  }
  for (; p < end; ++p) {
    int s = csr_src[p];
    float v = als[s] + aldd; v = v > 0.f ? v : 0.2f * v;
    float w = __expf(v);
    den += w;
    acc += w * bf2f(h2[(size_t)s * 64 + lane]);
  }
  float z = acc / (den + 1e-16f) + b2[lane];
  float zm = z;
#pragma unroll
  for (int off = 32; off; off >>= 1) zm = fmaxf(zm, __shfl_xor(zm, off, 64));
  float ex = __expf(z - zm), se = ex;
#pragma unroll
  for (int off = 32; off; off >>= 1) se += __shfl_xor(se, off, 64);
  out[(size_t)d * 64 + lane] = z - zm - __logf(se);
}

// ------------------------------- launch -----------------------------------
extern "C" void kernel_launch(void* const* d_in, const int* in_sizes, int n_in,
                              void* d_out, int out_size, void* d_ws, size_t ws_size,
                              hipStream_t stream) {
  const int N = in_sizes[0] / 256;   // 50000
  const int E = in_sizes[1] / 2;     // 800000
  const int ET = E + N;
  const int CS = (ET + NCHUNK - 1) / NCHUNK;
  const int NB = (N + 1023) / 1024;

  const float* x   = (const float*)d_in[0];
  const int*   ei  = (const int*)d_in[1];
  const float* W1  = (const float*)d_in[2];
  const float* as1 = (const float*)d_in[3];
  const float* ad1 = (const float*)d_in[4];
  const float* b1  = (const float*)d_in[5];
  const float* W2  = (const float*)d_in[6];
  const float* as2 = (const float*)d_in[7];
  const float* ad2 = (const float*)d_in[8];
  const float* b2  = (const float*)d_in[9];
  float* out = (float*)d_out;

  // workspace carve. h2b aliases h1b (dead after attn1).
  // hist (NCHUNK*N ints) aliases helu (dead after scatter2 / written by attn1).
  char* p = (char*)d_ws;
  unsigned short* h1b  = (unsigned short*)p; p += (size_t)N * 128 * 2;
  unsigned short* h2b  = h1b;                       // alias, [N][64]
  unsigned short* helu = (unsigned short*)p; p += (size_t)NCHUNK * N * 4;  // shared w/ hist
  int* hist = (int*)helu;
  unsigned short* Wt1  = (unsigned short*)p; p += (size_t)128 * 256 * 2;
  unsigned short* Wt2  = (unsigned short*)p; p += (size_t)64 * 128 * 2;
  float* als1 = (float*)p; p += (size_t)N * 8 * 4;
  float* ald1 = (float*)p; p += (size_t)N * 8 * 4;
  float* als2 = (float*)p; p += (size_t)N * 4;
  float* ald2 = (float*)p; p += (size_t)N * 4;
  int* deg     = (int*)p; p += (size_t)N * 4;
  int* rowptr  = (int*)p; p += (size_t)(N + 1) * 4;
  int* bsum    = (int*)p; p += 64 * 4;
  int* csr_src = (int*)p; p += (size_t)ET * 4;

  convw_kernel<<<(128 * 256 + 64 * 128 + 255) / 256, 256, 0, stream>>>(W1, W2, Wt1, Wt2);

  hist_kernel<<<NCHUNK * NRANGE, 512, 0, stream>>>(ei, hist, E, N, ET, CS);
  colscan_kernel<<<(N + 255) / 256, 256, 0, stream>>>(hist, deg, N);
  scan1_kernel<<<NB, 1024, 0, stream>>>(deg, rowptr, bsum, N);
  scan2_kernel<<<1, 64, 0, stream>>>(bsum, NB);
  scan3_kernel<<<(N + 256) / 256, 256, 0, stream>>>(rowptr, bsum, N, ET);
  scatter2_kernel<<<NCHUNK * NRANGE, 512, 0, stream>>>(ei, hist, rowptr, csr_src, E, N, ET, CS);

  gemm1_mfma<<<(N + 63) / 64, 256, 0, stream>>>(x, Wt1, h1b, N);
  dots1_kernel<<<(N + 3) / 4, 256, 0, stream>>>(h1b, as1, ad1, als1, ald1, N);
  attn1_kernel<<<(N + 3) / 4, 256, 0, stream>>>(h1b, als1, ald1, b1, rowptr, csr_src, helu, N);

  gemm2_mfma<<<(N + 63) / 64, 256, 0, stream>>>(helu, Wt2, h2b, N);
  dots2_kernel<<<(N + 3) / 4, 256, 0, stream>>>(h2b, as2, ad2, als2, ald2, N);
  attn2_kernel<<<(N + 3) / 4, 256, 0, stream>>>(h2b, als2, ald2, b2, rowptr, csr_src, out, N);
}

// Round 7
// 272.069 us; speedup vs baseline: 1.0899x; 1.0052x over previous
//
#include <hip/hip_runtime.h>
#include <hip/hip_bf16.h>

// ---------------------------------------------------------------------------
// GAT 2-layer forward on MI355X.
//   CSR build via atomic-free counting sort (LDS histograms + scans).
//   GEMMs: bf16 MFMA 16x16x32, A prefetched in registers (launch_bounds
//   keeps them live), B staged in LDS.
//   Attention: phase-split waves -- phase 1 computes distinct softmax
//   weights across lanes (no redundant exp), phase 2 shuffles weights and
//   gathers rows with quad-unrolled independent loads (4 in flight).
//   h1/helu/h2 stored bf16. Single-pass softmax (logits bounded).
// ---------------------------------------------------------------------------

typedef __attribute__((ext_vector_type(8))) short short8;
typedef __attribute__((ext_vector_type(4))) float f4;

#define NCHUNK 64      // edge chunks
#define NRANGE 4       // node ranges
#define RSIZE 16384    // nodes per range (64 KB LDS histogram)
#define G1PAD 136      // LDS row stride (shorts) for B tiles
#define G2PAD 136

__device__ __forceinline__ unsigned short f2bf(float f) {
  unsigned int u = __builtin_bit_cast(unsigned int, f);
  u += 0x7fffu + ((u >> 16) & 1u);             // round-nearest-even
  return (unsigned short)(u >> 16);
}
__device__ __forceinline__ float bf2f(unsigned short h) {
  unsigned int u = ((unsigned int)h) << 16;
  return __builtin_bit_cast(float, u);
}

// ------------------------- CSR build (atomic-free) -------------------------
__global__ __launch_bounds__(512) void hist_kernel(const int* __restrict__ ei,
                                                   int* __restrict__ hist,
                                                   int E, int N, int ET, int CS) {
  __shared__ int lh[RSIZE];
  const int c = blockIdx.x & (NCHUNK - 1);
  const int r = blockIdx.x >> 6;
  const int base = r * RSIZE;
  for (int i = threadIdx.x; i < RSIZE; i += 512) lh[i] = 0;
  __syncthreads();
  const int e0 = c * CS, e1 = min(e0 + CS, ET);
  for (int e = e0 + threadIdx.x; e < e1; e += 512) {
    int d = (e < E) ? ei[E + e] : (e - E);
    unsigned dl = (unsigned)(d - base);
    if (dl < RSIZE) atomicAdd(&lh[dl], 1);
  }
  __syncthreads();
  for (int i = threadIdx.x; i < RSIZE; i += 512) {
    int d = base + i;
    if (d < N) hist[c * N + d] = lh[i];
  }
}

__global__ __launch_bounds__(256) void colscan_kernel(int* __restrict__ hist,
                                                      int* __restrict__ deg, int N) {
  int d = blockIdx.x * 256 + threadIdx.x;
  if (d >= N) return;
  int run = 0;
#pragma unroll 8
  for (int c = 0; c < NCHUNK; ++c) {
    int v = hist[c * N + d];
    hist[c * N + d] = run;
    run += v;
  }
  deg[d] = run;
}

__global__ __launch_bounds__(1024) void scan1_kernel(const int* __restrict__ deg,
                                                     int* __restrict__ rowptr,
                                                     int* __restrict__ bsum, int N) {
  __shared__ int wtot[16];
  const int lane = threadIdx.x & 63, wid = threadIdx.x >> 6;
  int i = blockIdx.x * 1024 + threadIdx.x;
  int v = (i < N) ? deg[i] : 0;
  int incl = v;
#pragma unroll
  for (int off = 1; off < 64; off <<= 1) {
    int t = __shfl_up(incl, off, 64);
    if (lane >= off) incl += t;
  }
  if (lane == 63) wtot[wid] = incl;
  __syncthreads();
  int woff = 0;
#pragma unroll
  for (int w = 0; w < 16; ++w) woff += (w < wid) ? wtot[w] : 0;
  if (i < N) rowptr[i] = woff + incl - v;
  if (threadIdx.x == 1023) bsum[blockIdx.x] = woff + incl;
}

__global__ __launch_bounds__(64) void scan2_kernel(int* __restrict__ bsum, int NB) {
  int lane = threadIdx.x;
  int v = (lane < NB) ? bsum[lane] : 0;
  int incl = v;
#pragma unroll
  for (int off = 1; off < 64; off <<= 1) {
    int t = __shfl_up(incl, off, 64);
    if (lane >= off) incl += t;
  }
  if (lane < NB) bsum[lane] = incl - v;
}

__global__ __launch_bounds__(256) void scan3_kernel(int* __restrict__ rowptr,
                                                    const int* __restrict__ bsum,
                                                    int N, int ET) {
  int i = blockIdx.x * 256 + threadIdx.x;
  if (i < N) rowptr[i] += bsum[i >> 10];
  if (i == N) rowptr[N] = ET;
}

__global__ __launch_bounds__(512) void scatter2_kernel(const int* __restrict__ ei,
                                                       const int* __restrict__ hist,
                                                       const int* __restrict__ rowptr,
                                                       int* __restrict__ csr_src,
                                                       int E, int N, int ET, int CS) {
  __shared__ int lh[RSIZE];
  const int c = blockIdx.x & (NCHUNK - 1);
  const int r = blockIdx.x >> 6;
  const int base = r * RSIZE;
  for (int i = threadIdx.x; i < RSIZE; i += 512) {
    int d = base + i;
    lh[i] = (d < N) ? (rowptr[d] + hist[c * N + d]) : 0;
  }
  __syncthreads();
  const int e0 = c * CS, e1 = min(e0 + CS, ET);
  for (int e = e0 + threadIdx.x; e < e1; e += 512) {
    int s, d;
    if (e < E) { s = ei[e]; d = ei[E + e]; }
    else       { s = e - E; d = s; }
    unsigned dl = (unsigned)(d - base);
    if (dl < RSIZE) {
      int slot = atomicAdd(&lh[dl], 1);
      csr_src[slot] = s;
    }
  }
}

// ------------------- weight transpose + bf16 convert ----------------------
__global__ __launch_bounds__(256) void convw_kernel(const float* __restrict__ W1,
                                                    const float* __restrict__ W2,
                                                    unsigned short* __restrict__ Wt1,
                                                    unsigned short* __restrict__ Wt2) {
  int i = blockIdx.x * blockDim.x + threadIdx.x;
  if (i < 128 * 256) {
    int n = i >> 8, k = i & 255;
    Wt1[i] = f2bf(W1[k * 128 + n]);
  } else {
    int j = i - 128 * 256;
    if (j < 64 * 128) {
      int n = j >> 7, k = j & 127;
      Wt2[j] = f2bf(W2[k * 64 + n]);
    }
  }
}

// ------------------------------ GEMM1 (MFMA) ------------------------------
__global__ __launch_bounds__(256, 3) void gemm1_mfma(const float* __restrict__ X,
                                                     const unsigned short* __restrict__ Wt,
                                                     unsigned short* __restrict__ H,
                                                     int M) {
  __shared__ unsigned short bl[128 * G1PAD];
  const int t = threadIdx.x;
  const int wv = t >> 6, ln = t & 63;
  const int ml = ln & 15, q = ln >> 4;
  const int r0 = blockIdx.x * 64 + wv * 16;
  const int arow = min(r0 + ml, M - 1);
  const float* xp = X + (size_t)arow * 256 + q * 8;

  float4 a0[8], a1[8];
#pragma unroll
  for (int s = 0; s < 8; ++s) {
    a0[s] = *(const float4*)(xp + s * 32);
    a1[s] = *(const float4*)(xp + s * 32 + 4);
  }

  f4 acc[8];
#pragma unroll
  for (int b = 0; b < 8; ++b) acc[b] = (f4)0.f;

  const int crow = t >> 1, coff = (t & 1) * 64;
#pragma unroll
  for (int half = 0; half < 2; ++half) {
    __syncthreads();
    {
      const unsigned short* src = Wt + (size_t)crow * 256 + half * 128 + coff;
      unsigned short* dst = &bl[crow * G1PAD + coff];
#pragma unroll
      for (int c = 0; c < 8; ++c)
        *(short8*)(dst + c * 8) = *(const short8*)(src + c * 8);
    }
    __syncthreads();
#pragma unroll
    for (int sl = 0; sl < 4; ++sl) {
      const int s = half * 4 + sl;
      short8 av;
      av[0] = (short)f2bf(a0[s].x); av[1] = (short)f2bf(a0[s].y);
      av[2] = (short)f2bf(a0[s].z); av[3] = (short)f2bf(a0[s].w);
      av[4] = (short)f2bf(a1[s].x); av[5] = (short)f2bf(a1[s].y);
      av[6] = (short)f2bf(a1[s].z); av[7] = (short)f2bf(a1[s].w);
#pragma unroll
      for (int b = 0; b < 8; ++b) {
        short8 bfr = *(const short8*)&bl[(b * 16 + ml) * G1PAD + sl * 32 + q * 8];
        acc[b] = __builtin_amdgcn_mfma_f32_16x16x32_bf16(av, bfr, acc[b], 0, 0, 0);
      }
    }
  }

#pragma unroll
  for (int i = 0; i < 4; ++i) {
    int rr = r0 + q * 4 + i;
    if (rr < M) {
#pragma unroll
      for (int b = 0; b < 8; ++b)
        H[(size_t)rr * 128 + b * 16 + ml] = f2bf(acc[b][i]);
    }
  }
}

// ------------------------------ GEMM2 (MFMA) ------------------------------
__global__ __launch_bounds__(256, 4) void gemm2_mfma(const unsigned short* __restrict__ Xb,
                                                     const unsigned short* __restrict__ Wt,
                                                     unsigned short* __restrict__ H,
                                                     int M) {
  __shared__ unsigned short bl[64 * G2PAD];
  const int t = threadIdx.x;
  const int wv = t >> 6, ln = t & 63;
  const int ml = ln & 15, q = ln >> 4;
  const int r0 = blockIdx.x * 64 + wv * 16;
  const int arow = min(r0 + ml, M - 1);
  const unsigned short* xp = Xb + (size_t)arow * 128 + q * 8;

  short8 av[4];
#pragma unroll
  for (int s = 0; s < 4; ++s) av[s] = *(const short8*)(xp + s * 32);

  {
    const int crow = t >> 2, coff = (t & 3) * 32;
    const unsigned short* src = Wt + (size_t)crow * 128 + coff;
    unsigned short* dst = &bl[crow * G2PAD + coff];
#pragma unroll
    for (int c = 0; c < 4; ++c)
      *(short8*)(dst + c * 8) = *(const short8*)(src + c * 8);
  }
  __syncthreads();

  f4 acc[4];
#pragma unroll
  for (int b = 0; b < 4; ++b) acc[b] = (f4)0.f;

#pragma unroll
  for (int s = 0; s < 4; ++s) {
#pragma unroll
    for (int b = 0; b < 4; ++b) {
      short8 bfr = *(const short8*)&bl[(b * 16 + ml) * G2PAD + s * 32 + q * 8];
      acc[b] = __builtin_amdgcn_mfma_f32_16x16x32_bf16(av[s], bfr, acc[b], 0, 0, 0);
    }
  }

#pragma unroll
  for (int i = 0; i < 4; ++i) {
    int rr = r0 + q * 4 + i;
    if (rr < M) {
#pragma unroll
      for (int b = 0; b < 4; ++b)
        H[(size_t)rr * 64 + b * 16 + ml] = f2bf(acc[b][i]);
    }
  }
}

// ------------------------------- dots -------------------------------------
__global__ __launch_bounds__(256) void dots1_kernel(const unsigned short* __restrict__ h1,
                                                    const float* __restrict__ as,
                                                    const float* __restrict__ ad,
                                                    float* __restrict__ als,
                                                    float* __restrict__ ald, int N) {
  int wave = (blockIdx.x * blockDim.x + threadIdx.x) >> 6;
  int lane = threadIdx.x & 63;
  if (wave >= N) return;
  float x0 = bf2f(h1[(size_t)wave * 128 + lane]);
  float x1 = bf2f(h1[(size_t)wave * 128 + 64 + lane]);
  float s0 = x0 * as[lane], s1 = x1 * as[64 + lane];
  float d0 = x0 * ad[lane], d1 = x1 * ad[64 + lane];
#pragma unroll
  for (int off = 8; off; off >>= 1) {
    s0 += __shfl_down(s0, off, 16); s1 += __shfl_down(s1, off, 16);
    d0 += __shfl_down(d0, off, 16); d1 += __shfl_down(d1, off, 16);
  }
  if ((lane & 15) == 0) {
    int h = lane >> 4;
    als[wave * 8 + h] = s0; als[wave * 8 + 4 + h] = s1;
    ald[wave * 8 + h] = d0; ald[wave * 8 + 4 + h] = d1;
  }
}

__global__ __launch_bounds__(256) void dots2_kernel(const unsigned short* __restrict__ h2,
                                                    const float* __restrict__ as,
                                                    const float* __restrict__ ad,
                                                    float* __restrict__ als,
                                                    float* __restrict__ ald, int N) {
  int wave = (blockIdx.x * blockDim.x + threadIdx.x) >> 6;
  int lane = threadIdx.x & 63;
  if (wave >= N) return;
  float x = bf2f(h2[(size_t)wave * 64 + lane]);
  float s = x * as[lane], d = x * ad[lane];
#pragma unroll
  for (int off = 32; off; off >>= 1) {
    s += __shfl_xor(s, off, 64);
    d += __shfl_xor(d, off, 64);
  }
  if (lane == 0) { als[wave] = s; ald[wave] = d; }
}

// ------------------------------- attn1 ------------------------------------
// one wave per dst. Phase 1 per 8-edge batch: lane (e=l>>3, h=l&7) computes
// one distinct weight (no redundant exp). Phase 2: shuffle w (bpermute) and
// src (readlane, uniform), gather h1 row (features 2l,2l+1), accumulate.
// Invalid tail lanes contribute exactly 0.0f -> sums bitwise unchanged.
__global__ __launch_bounds__(256) void attn1_kernel(
    const unsigned short* __restrict__ h1, const float* __restrict__ als,
    const float* __restrict__ ald, const float* __restrict__ b1,
    const int* __restrict__ rowptr, const int* __restrict__ csr_src,
    unsigned short* __restrict__ helu, int N) {
  int d = __builtin_amdgcn_readfirstlane(
      (blockIdx.x * blockDim.x + threadIdx.x) >> 6);
  int lane = threadIdx.x & 63;
  if (d >= N) return;
  const int hh = lane >> 3;            // phase-2 head (feature pair 2l,2l+1)
  const int hw = lane & 7;             // phase-1 head
  const int ew = lane >> 3;            // phase-1 edge-in-batch
  const float aldp = ald[d * 8 + hw];
  const int beg = rowptr[d], end = rowptr[d + 1];
  const unsigned short* h1l = h1 + 2 * lane;
  float den = 0.f, ax = 0.f, ay = 0.f;

  for (int p0 = beg; p0 < end; p0 += 8) {
    int idx = p0 + ew;
    int se = csr_src[idx < end ? idx : end - 1];
    float v = als[se * 8 + hw] + aldp;
    v = fmaxf(v, 0.2f * v);                      // leaky_relu
    float w = (idx < end) ? __expf(v) : 0.f;
#pragma unroll
    for (int j = 0; j < 4; ++j) {
      float wj = __shfl(w, j * 8 + hh);
      int sj = __shfl(se, j * 8);
      ushort2 g = *(const ushort2*)(h1l + (size_t)sj * 128);
      den += wj; ax += wj * bf2f(g.x); ay += wj * bf2f(g.y);
    }
    if (p0 + 4 < end) {
#pragma unroll
      for (int j = 4; j < 8; ++j) {
        float wj = __shfl(w, j * 8 + hh);
        int sj = __shfl(se, j * 8);
        ushort2 g = *(const ushort2*)(h1l + (size_t)sj * 128);
        den += wj; ax += wj * bf2f(g.x); ay += wj * bf2f(g.y);
      }
    }
  }

  float inv = 1.0f / (den + 1e-16f);
  float2 bb = *(const float2*)(b1 + 2 * lane);
  float o0 = ax * inv + bb.x;
  float o1 = ay * inv + bb.y;
  o0 = o0 > 0.f ? o0 : __expf(o0) - 1.0f;        // ELU
  o1 = o1 > 0.f ? o1 : __expf(o1) - 1.0f;
  ushort2 ov; ov.x = f2bf(o0); ov.y = f2bf(o1);
  *(ushort2*)(helu + (size_t)d * 128 + 2 * lane) = ov;
}

// ------------------------------- attn2 ------------------------------------
// one wave per dst. Phase 1 per 64-edge batch: lane e computes w[e]
// (was 64x-redundant exp). Phase 2: quad-unrolled gather+accumulate.
__global__ __launch_bounds__(256) void attn2_kernel(
    const unsigned short* __restrict__ h2, const float* __restrict__ als,
    const float* __restrict__ ald, const float* __restrict__ b2,
    const int* __restrict__ rowptr, const int* __restrict__ csr_src,
    float* __restrict__ out, int N) {
  int d = __builtin_amdgcn_readfirstlane(
      (blockIdx.x * blockDim.x + threadIdx.x) >> 6);
  int lane = threadIdx.x & 63;
  if (d >= N) return;
  const float aldd = ald[d];
  const int beg = rowptr[d], end = rowptr[d + 1];
  const unsigned short* h2l = h2 + lane;
  float den = 0.f, acc = 0.f;

  for (int p0 = beg; p0 < end; p0 += 64) {
    int idx = p0 + lane;
    int se = csr_src[idx < end ? idx : end - 1];
    float v = als[se] + aldd;
    v = fmaxf(v, 0.2f * v);
    float w = (idx < end) ? __expf(v) : 0.f;
    int cnt = min(64, end - p0);
    for (int j0 = 0; j0 < cnt; j0 += 4) {
#pragma unroll
      for (int j = 0; j < 4; ++j) {
        float wj = __shfl(w, j0 + j);
        int sj = __shfl(se, j0 + j);
        float g = bf2f(h2l[(size_t)sj * 64]);
        den += wj; acc += wj * g;
      }
    }
  }

  float z = acc / (den + 1e-16f) + b2[lane];
  float zm = z;
#pragma unroll
  for (int off = 32; off; off >>= 1) zm = fmaxf(zm, __shfl_xor(zm, off, 64));
  float ex = __expf(z - zm), se2 = ex;
#pragma unroll
  for (int off = 32; off; off >>= 1) se2 += __shfl_xor(se2, off, 64);
  out[(size_t)d * 64 + lane] = z - zm - __logf(se2);
}

// ------------------------------- launch -----------------------------------
extern "C" void kernel_launch(void* const* d_in, const int* in_sizes, int n_in,
                              void* d_out, int out_size, void* d_ws, size_t ws_size,
                              hipStream_t stream) {
  const int N = in_sizes[0] / 256;   // 50000
  const int E = in_sizes[1] / 2;     // 800000
  const int ET = E + N;
  const int CS = (ET + NCHUNK - 1) / NCHUNK;
  const int NB = (N + 1023) / 1024;

  const float* x   = (const float*)d_in[0];
  const int*   ei  = (const int*)d_in[1];
  const float* W1  = (const float*)d_in[2];
  const float* as1 = (const float*)d_in[3];
  const float* ad1 = (const float*)d_in[4];
  const float* b1  = (const float*)d_in[5];
  const float* W2  = (const float*)d_in[6];
  const float* as2 = (const float*)d_in[7];
  const float* ad2 = (const float*)d_in[8];
  const float* b2  = (const float*)d_in[9];
  float* out = (float*)d_out;

  // workspace carve. h2b aliases h1b (dead after attn1).
  // hist (NCHUNK*N ints) aliases helu (dead after scatter2 / written by attn1).
  char* p = (char*)d_ws;
  unsigned short* h1b  = (unsigned short*)p; p += (size_t)N * 128 * 2;
  unsigned short* h2b  = h1b;                       // alias, [N][64]
  unsigned short* helu = (unsigned short*)p; p += (size_t)NCHUNK * N * 4;  // shared w/ hist
  int* hist = (int*)helu;
  unsigned short* Wt1  = (unsigned short*)p; p += (size_t)128 * 256 * 2;
  unsigned short* Wt2  = (unsigned short*)p; p += (size_t)64 * 128 * 2;
  float* als1 = (float*)p; p += (size_t)N * 8 * 4;
  float* ald1 = (float*)p; p += (size_t)N * 8 * 4;
  float* als2 = (float*)p; p += (size_t)N * 4;
  float* ald2 = (float*)p; p += (size_t)N * 4;
  int* deg     = (int*)p; p += (size_t)N * 4;
  int* rowptr  = (int*)p; p += (size_t)(N + 1) * 4;
  int* bsum    = (int*)p; p += 64 * 4;
  int* csr_src = (int*)p; p += (size_t)ET * 4;

  convw_kernel<<<(128 * 256 + 64 * 128 + 255) / 256, 256, 0, stream>>>(W1, W2, Wt1, Wt2);

  hist_kernel<<<NCHUNK * NRANGE, 512, 0, stream>>>(ei, hist, E, N, ET, CS);
  colscan_kernel<<<(N + 255) / 256, 256, 0, stream>>>(hist, deg, N);
  scan1_kernel<<<NB, 1024, 0, stream>>>(deg, rowptr, bsum, N);
  scan2_kernel<<<1, 64, 0, stream>>>(bsum, NB);
  scan3_kernel<<<(N + 256) / 256, 256, 0, stream>>>(rowptr, bsum, N, ET);
  scatter2_kernel<<<NCHUNK * NRANGE, 512, 0, stream>>>(ei, hist, rowptr, csr_src, E, N, ET, CS);

  gemm1_mfma<<<(N + 63) / 64, 256, 0, stream>>>(x, Wt1, h1b, N);
  dots1_kernel<<<(N + 3) / 4, 256, 0, stream>>>(h1b, as1, ad1, als1, ald1, N);
  attn1_kernel<<<(N + 3) / 4, 256, 0, stream>>>(h1b, als1, ald1, b1, rowptr, csr_src, helu, N);

  gemm2_mfma<<<(N + 63) / 64, 256, 0, stream>>>(helu, Wt2, h2b, N);
  dots2_kernel<<<(N + 3) / 4, 256, 0, stream>>>(h2b, as2, ad2, als2, ald2, N);
  attn2_kernel<<<(N + 3) / 4, 256, 0, stream>>>(h2b, als2, ald2, b2, rowptr, csr_src, out, N);
}

// Round 8
// 266.197 us; speedup vs baseline: 1.1139x; 1.0221x over previous
//
#include <hip/hip_runtime.h>
#include <hip/hip_bf16.h>

// ---------------------------------------------------------------------------
// GAT 2-layer forward on MI355X.
//   CSR build via atomic-free counting sort (LDS histograms + scans).
//   GEMMs: bf16 MFMA 16x16x32, A prefetched in registers, B staged in LDS.
//   h1/h2 stored FP8 e4m3 (OCP): halves gather bytes (h2 becomes
//   L2-resident), decode = 1 HW cvt instr. helu stays bf16 for GEMM2.
//   Attention: phase-split waves (distinct exp per lane) + quad-unrolled
//   independent gathers. Single-pass softmax (logits bounded).
// ---------------------------------------------------------------------------

typedef __attribute__((ext_vector_type(8))) short short8;
typedef __attribute__((ext_vector_type(4))) float f4;
typedef __attribute__((ext_vector_type(2))) float float2v;

#define NCHUNK 64      // edge chunks
#define NRANGE 4       // node ranges
#define RSIZE 16384    // nodes per range (64 KB LDS histogram)
#define G1PAD 136      // LDS row stride (shorts) for B tiles
#define G2PAD 136

__device__ __forceinline__ unsigned short f2bf(float f) {
  unsigned int u = __builtin_bit_cast(unsigned int, f);
  u += 0x7fffu + ((u >> 16) & 1u);             // round-nearest-even
  return (unsigned short)(u >> 16);
}
__device__ __forceinline__ float bf2f(unsigned short h) {
  unsigned int u = ((unsigned int)h) << 16;
  return __builtin_bit_cast(float, u);
}

// float -> fp8 e4m3fn, RNE, saturating (software; used in GEMM epilogues)
__device__ __forceinline__ unsigned char f2fp8(float f) {
  unsigned int u = __builtin_bit_cast(unsigned int, f);
  unsigned int s = (u >> 24) & 0x80u;
  float a = fabsf(f);
  a = fminf(a, 448.f);
  if (a < 0.015625f) {                  // subnormal: step 2^-9 (m=8 ->2^-6 ok)
    int m = (int)rintf(a * 512.f);
    return (unsigned char)(s | (unsigned)m);
  }
  unsigned int ub = __builtin_bit_cast(unsigned int, a);
  ub += 0xFFFFFu + ((ub >> 20) & 1u);   // RNE into 3-bit mantissa
  unsigned int e = (ub >> 23) - 120u;
  unsigned int m = (ub >> 20) & 7u;
  if (e > 15u) { e = 15u; m = 6u; }     // clamp to 448
  return (unsigned char)(s | (e << 3) | m);
}

// ------------------------- CSR build (atomic-free) -------------------------
__global__ __launch_bounds__(512) void hist_kernel(const int* __restrict__ ei,
                                                   int* __restrict__ hist,
                                                   int E, int N, int ET, int CS) {
  __shared__ int lh[RSIZE];
  const int c = blockIdx.x & (NCHUNK - 1);
  const int r = blockIdx.x >> 6;
  const int base = r * RSIZE;
  for (int i = threadIdx.x; i < RSIZE; i += 512) lh[i] = 0;
  __syncthreads();
  const int e0 = c * CS, e1 = min(e0 + CS, ET);
  for (int e = e0 + threadIdx.x; e < e1; e += 512) {
    int d = (e < E) ? ei[E + e] : (e - E);
    unsigned dl = (unsigned)(d - base);
    if (dl < RSIZE) atomicAdd(&lh[dl], 1);
  }
  __syncthreads();
  for (int i = threadIdx.x; i < RSIZE; i += 512) {
    int d = base + i;
    if (d < N) hist[c * N + d] = lh[i];
  }
}

__global__ __launch_bounds__(256) void colscan_kernel(int* __restrict__ hist,
                                                      int* __restrict__ deg, int N) {
  int d = blockIdx.x * 256 + threadIdx.x;
  if (d >= N) return;
  int run = 0;
#pragma unroll 8
  for (int c = 0; c < NCHUNK; ++c) {
    int v = hist[c * N + d];
    hist[c * N + d] = run;
    run += v;
  }
  deg[d] = run;
}

__global__ __launch_bounds__(1024) void scan1_kernel(const int* __restrict__ deg,
                                                     int* __restrict__ rowptr,
                                                     int* __restrict__ bsum, int N) {
  __shared__ int wtot[16];
  const int lane = threadIdx.x & 63, wid = threadIdx.x >> 6;
  int i = blockIdx.x * 1024 + threadIdx.x;
  int v = (i < N) ? deg[i] : 0;
  int incl = v;
#pragma unroll
  for (int off = 1; off < 64; off <<= 1) {
    int t = __shfl_up(incl, off, 64);
    if (lane >= off) incl += t;
  }
  if (lane == 63) wtot[wid] = incl;
  __syncthreads();
  int woff = 0;
#pragma unroll
  for (int w = 0; w < 16; ++w) woff += (w < wid) ? wtot[w] : 0;
  if (i < N) rowptr[i] = woff + incl - v;
  if (threadIdx.x == 1023) bsum[blockIdx.x] = woff + incl;
}

__global__ __launch_bounds__(64) void scan2_kernel(int* __restrict__ bsum, int NB) {
  int lane = threadIdx.x;
  int v = (lane < NB) ? bsum[lane] : 0;
  int incl = v;
#pragma unroll
  for (int off = 1; off < 64; off <<= 1) {
    int t = __shfl_up(incl, off, 64);
    if (lane >= off) incl += t;
  }
  if (lane < NB) bsum[lane] = incl - v;
}

__global__ __launch_bounds__(256) void scan3_kernel(int* __restrict__ rowptr,
                                                    const int* __restrict__ bsum,
                                                    int N, int ET) {
  int i = blockIdx.x * 256 + threadIdx.x;
  if (i < N) rowptr[i] += bsum[i >> 10];
  if (i == N) rowptr[N] = ET;
}

__global__ __launch_bounds__(512) void scatter2_kernel(const int* __restrict__ ei,
                                                       const int* __restrict__ hist,
                                                       const int* __restrict__ rowptr,
                                                       int* __restrict__ csr_src,
                                                       int E, int N, int ET, int CS) {
  __shared__ int lh[RSIZE];
  const int c = blockIdx.x & (NCHUNK - 1);
  const int r = blockIdx.x >> 6;
  const int base = r * RSIZE;
  for (int i = threadIdx.x; i < RSIZE; i += 512) {
    int d = base + i;
    lh[i] = (d < N) ? (rowptr[d] + hist[c * N + d]) : 0;
  }
  __syncthreads();
  const int e0 = c * CS, e1 = min(e0 + CS, ET);
  for (int e = e0 + threadIdx.x; e < e1; e += 512) {
    int s, d;
    if (e < E) { s = ei[e]; d = ei[E + e]; }
    else       { s = e - E; d = s; }
    unsigned dl = (unsigned)(d - base);
    if (dl < RSIZE) {
      int slot = atomicAdd(&lh[dl], 1);
      csr_src[slot] = s;
    }
  }
}

// ------------------- weight transpose + bf16 convert ----------------------
__global__ __launch_bounds__(256) void convw_kernel(const float* __restrict__ W1,
                                                    const float* __restrict__ W2,
                                                    unsigned short* __restrict__ Wt1,
                                                    unsigned short* __restrict__ Wt2) {
  int i = blockIdx.x * blockDim.x + threadIdx.x;
  if (i < 128 * 256) {
    int n = i >> 8, k = i & 255;
    Wt1[i] = f2bf(W1[k * 128 + n]);
  } else {
    int j = i - 128 * 256;
    if (j < 64 * 128) {
      int n = j >> 7, k = j & 127;
      Wt2[j] = f2bf(W2[k * 64 + n]);
    }
  }
}

// ------------------------------ GEMM1 (MFMA) ------------------------------
// H1f8[M,128] = fp8( X[M,256] @ W1 ).
__global__ __launch_bounds__(256, 3) void gemm1_mfma(const float* __restrict__ X,
                                                     const unsigned short* __restrict__ Wt,
                                                     unsigned char* __restrict__ H,
                                                     int M) {
  __shared__ unsigned short bl[128 * G1PAD];
  const int t = threadIdx.x;
  const int wv = t >> 6, ln = t & 63;
  const int ml = ln & 15, q = ln >> 4;
  const int r0 = blockIdx.x * 64 + wv * 16;
  const int arow = min(r0 + ml, M - 1);
  const float* xp = X + (size_t)arow * 256 + q * 8;

  float4 a0[8], a1[8];
#pragma unroll
  for (int s = 0; s < 8; ++s) {
    a0[s] = *(const float4*)(xp + s * 32);
    a1[s] = *(const float4*)(xp + s * 32 + 4);
  }

  f4 acc[8];
#pragma unroll
  for (int b = 0; b < 8; ++b) acc[b] = (f4)0.f;

  const int crow = t >> 1, coff = (t & 1) * 64;
#pragma unroll
  for (int half = 0; half < 2; ++half) {
    __syncthreads();
    {
      const unsigned short* src = Wt + (size_t)crow * 256 + half * 128 + coff;
      unsigned short* dst = &bl[crow * G1PAD + coff];
#pragma unroll
      for (int c = 0; c < 8; ++c)
        *(short8*)(dst + c * 8) = *(const short8*)(src + c * 8);
    }
    __syncthreads();
#pragma unroll
    for (int sl = 0; sl < 4; ++sl) {
      const int s = half * 4 + sl;
      short8 av;
      av[0] = (short)f2bf(a0[s].x); av[1] = (short)f2bf(a0[s].y);
      av[2] = (short)f2bf(a0[s].z); av[3] = (short)f2bf(a0[s].w);
      av[4] = (short)f2bf(a1[s].x); av[5] = (short)f2bf(a1[s].y);
      av[6] = (short)f2bf(a1[s].z); av[7] = (short)f2bf(a1[s].w);
#pragma unroll
      for (int b = 0; b < 8; ++b) {
        short8 bfr = *(const short8*)&bl[(b * 16 + ml) * G1PAD + sl * 32 + q * 8];
        acc[b] = __builtin_amdgcn_mfma_f32_16x16x32_bf16(av, bfr, acc[b], 0, 0, 0);
      }
    }
  }

#pragma unroll
  for (int i = 0; i < 4; ++i) {
    int rr = r0 + q * 4 + i;
    if (rr < M) {
#pragma unroll
      for (int b = 0; b < 8; ++b)
        H[(size_t)rr * 128 + b * 16 + ml] = f2fp8(acc[b][i]);
    }
  }
}

// ------------------------------ GEMM2 (MFMA) ------------------------------
// H2f8[M,64] = fp8( helu[M,128](bf16) @ W2 ).
__global__ __launch_bounds__(256, 4) void gemm2_mfma(const unsigned short* __restrict__ Xb,
                                                     const unsigned short* __restrict__ Wt,
                                                     unsigned char* __restrict__ H,
                                                     int M) {
  __shared__ unsigned short bl[64 * G2PAD];
  const int t = threadIdx.x;
  const int wv = t >> 6, ln = t & 63;
  const int ml = ln & 15, q = ln >> 4;
  const int r0 = blockIdx.x * 64 + wv * 16;
  const int arow = min(r0 + ml, M - 1);
  const unsigned short* xp = Xb + (size_t)arow * 128 + q * 8;

  short8 av[4];
#pragma unroll
  for (int s = 0; s < 4; ++s) av[s] = *(const short8*)(xp + s * 32);

  {
    const int crow = t >> 2, coff = (t & 3) * 32;
    const unsigned short* src = Wt + (size_t)crow * 128 + coff;
    unsigned short* dst = &bl[crow * G2PAD + coff];
#pragma unroll
    for (int c = 0; c < 4; ++c)
      *(short8*)(dst + c * 8) = *(const short8*)(src + c * 8);
  }
  __syncthreads();

  f4 acc[4];
#pragma unroll
  for (int b = 0; b < 4; ++b) acc[b] = (f4)0.f;

#pragma unroll
  for (int s = 0; s < 4; ++s) {
#pragma unroll
    for (int b = 0; b < 4; ++b) {
      short8 bfr = *(const short8*)&bl[(b * 16 + ml) * G2PAD + s * 32 + q * 8];
      acc[b] = __builtin_amdgcn_mfma_f32_16x16x32_bf16(av[s], bfr, acc[b], 0, 0, 0);
    }
  }

#pragma unroll
  for (int i = 0; i < 4; ++i) {
    int rr = r0 + q * 4 + i;
    if (rr < M) {
#pragma unroll
      for (int b = 0; b < 4; ++b)
        H[(size_t)rr * 64 + b * 16 + ml] = f2fp8(acc[b][i]);
    }
  }
}

// ------------------------------- dots -------------------------------------
// lane covers cols {2l,2l+1} (same head l>>3); reduce over 8 lanes per head.
__global__ __launch_bounds__(256) void dots1_kernel(const unsigned char* __restrict__ h1,
                                                    const float* __restrict__ as,
                                                    const float* __restrict__ ad,
                                                    float* __restrict__ als,
                                                    float* __restrict__ ald, int N) {
  int wave = (blockIdx.x * blockDim.x + threadIdx.x) >> 6;
  int lane = threadIdx.x & 63;
  if (wave >= N) return;
  unsigned short pk = *(const unsigned short*)(h1 + (size_t)wave * 128 + 2 * lane);
  float2v g = __builtin_amdgcn_cvt_pk_f32_fp8(pk, false);
  float s = g.x * as[2 * lane] + g.y * as[2 * lane + 1];
  float d = g.x * ad[2 * lane] + g.y * ad[2 * lane + 1];
#pragma unroll
  for (int off = 1; off < 8; off <<= 1) {
    s += __shfl_xor(s, off, 8);
    d += __shfl_xor(d, off, 8);
  }
  if ((lane & 7) == 0) {
    int h = lane >> 3;
    als[wave * 8 + h] = s;
    ald[wave * 8 + h] = d;
  }
}

__global__ __launch_bounds__(256) void dots2_kernel(const unsigned char* __restrict__ h2,
                                                    const float* __restrict__ as,
                                                    const float* __restrict__ ad,
                                                    float* __restrict__ als,
                                                    float* __restrict__ ald, int N) {
  int wave = (blockIdx.x * blockDim.x + threadIdx.x) >> 6;
  int lane = threadIdx.x & 63;
  if (wave >= N) return;
  float x = __builtin_amdgcn_cvt_f32_fp8(h2[(size_t)wave * 64 + lane], 0);
  float s = x * as[lane], d = x * ad[lane];
#pragma unroll
  for (int off = 32; off; off >>= 1) {
    s += __shfl_xor(s, off, 64);
    d += __shfl_xor(d, off, 64);
  }
  if (lane == 0) { als[wave] = s; ald[wave] = d; }
}

// ------------------------------- attn1 ------------------------------------
// one wave per dst. Phase 1 per 8-edge batch: lane (e=l>>3, h=l&7) computes
// one distinct weight. Phase 2: shuffle w/src, gather fp8 pair (cols 2l,2l+1),
// decode with one v_cvt_pk_f32_fp8, accumulate. Tail lanes contribute 0.0f.
__global__ __launch_bounds__(256) void attn1_kernel(
    const unsigned char* __restrict__ h1, const float* __restrict__ als,
    const float* __restrict__ ald, const float* __restrict__ b1,
    const int* __restrict__ rowptr, const int* __restrict__ csr_src,
    unsigned short* __restrict__ helu, int N) {
  int d = __builtin_amdgcn_readfirstlane(
      (blockIdx.x * blockDim.x + threadIdx.x) >> 6);
  int lane = threadIdx.x & 63;
  if (d >= N) return;
  const int hh = lane >> 3;            // phase-2 head (feature pair 2l,2l+1)
  const int hw = lane & 7;             // phase-1 head
  const int ew = lane >> 3;            // phase-1 edge-in-batch
  const float aldp = ald[d * 8 + hw];
  const int beg = rowptr[d], end = rowptr[d + 1];
  const unsigned char* h1l = h1 + 2 * lane;
  float den = 0.f, ax = 0.f, ay = 0.f;

  for (int p0 = beg; p0 < end; p0 += 8) {
    int idx = p0 + ew;
    int se = csr_src[idx < end ? idx : end - 1];
    float v = als[se * 8 + hw] + aldp;
    v = fmaxf(v, 0.2f * v);                      // leaky_relu
    float w = (idx < end) ? __expf(v) : 0.f;
#pragma unroll
    for (int j = 0; j < 4; ++j) {
      float wj = __shfl(w, j * 8 + hh);
      int sj = __shfl(se, j * 8);
      unsigned short pk = *(const unsigned short*)(h1l + (size_t)sj * 128);
      float2v g = __builtin_amdgcn_cvt_pk_f32_fp8(pk, false);
      den += wj; ax += wj * g.x; ay += wj * g.y;
    }
    if (p0 + 4 < end) {
#pragma unroll
      for (int j = 4; j < 8; ++j) {
        float wj = __shfl(w, j * 8 + hh);
        int sj = __shfl(se, j * 8);
        unsigned short pk = *(const unsigned short*)(h1l + (size_t)sj * 128);
        float2v g = __builtin_amdgcn_cvt_pk_f32_fp8(pk, false);
        den += wj; ax += wj * g.x; ay += wj * g.y;
      }
    }
  }

  float inv = 1.0f / (den + 1e-16f);
  float2 bb = *(const float2*)(b1 + 2 * lane);
  float o0 = ax * inv + bb.x;
  float o1 = ay * inv + bb.y;
  o0 = o0 > 0.f ? o0 : __expf(o0) - 1.0f;        // ELU
  o1 = o1 > 0.f ? o1 : __expf(o1) - 1.0f;
  ushort2 ov; ov.x = f2bf(o0); ov.y = f2bf(o1);
  *(ushort2*)(helu + (size_t)d * 128 + 2 * lane) = ov;
}

// ------------------------------- attn2 ------------------------------------
// one wave per dst; fp8 h2 (3.2 MB -> L2-resident). Phase 1: lane e computes
// w[e]; phase 2: quad-unrolled byte-gather + cvt + accumulate.
__global__ __launch_bounds__(256) void attn2_kernel(
    const unsigned char* __restrict__ h2, const float* __restrict__ als,
    const float* __restrict__ ald, const float* __restrict__ b2,
    const int* __restrict__ rowptr, const int* __restrict__ csr_src,
    float* __restrict__ out, int N) {
  int d = __builtin_amdgcn_readfirstlane(
      (blockIdx.x * blockDim.x + threadIdx.x) >> 6);
  int lane = threadIdx.x & 63;
  if (d >= N) return;
  const float aldd = ald[d];
  const int beg = rowptr[d], end = rowptr[d + 1];
  const unsigned char* h2l = h2 + lane;
  float den = 0.f, acc = 0.f;

  for (int p0 = beg; p0 < end; p0 += 64) {
    int idx = p0 + lane;
    int se = csr_src[idx < end ? idx : end - 1];
    float v = als[se] + aldd;
    v = fmaxf(v, 0.2f * v);
    float w = (idx < end) ? __expf(v) : 0.f;
    int cnt = min(64, end - p0);
    for (int j0 = 0; j0 < cnt; j0 += 4) {
#pragma unroll
      for (int j = 0; j < 4; ++j) {
        float wj = __shfl(w, j0 + j);
        int sj = __shfl(se, j0 + j);
        float g = __builtin_amdgcn_cvt_f32_fp8(h2l[(size_t)sj * 64], 0);
        den += wj; acc += wj * g;
      }
    }
  }

  float z = acc / (den + 1e-16f) + b2[lane];
  float zm = z;
#pragma unroll
  for (int off = 32; off; off >>= 1) zm = fmaxf(zm, __shfl_xor(zm, off, 64));
  float ex = __expf(z - zm), se2 = ex;
#pragma unroll
  for (int off = 32; off; off >>= 1) se2 += __shfl_xor(se2, off, 64);
  out[(size_t)d * 64 + lane] = z - zm - __logf(se2);
}

// ------------------------------- launch -----------------------------------
extern "C" void kernel_launch(void* const* d_in, const int* in_sizes, int n_in,
                              void* d_out, int out_size, void* d_ws, size_t ws_size,
                              hipStream_t stream) {
  const int N = in_sizes[0] / 256;   // 50000
  const int E = in_sizes[1] / 2;     // 800000
  const int ET = E + N;
  const int CS = (ET + NCHUNK - 1) / NCHUNK;
  const int NB = (N + 1023) / 1024;

  const float* x   = (const float*)d_in[0];
  const int*   ei  = (const int*)d_in[1];
  const float* W1  = (const float*)d_in[2];
  const float* as1 = (const float*)d_in[3];
  const float* ad1 = (const float*)d_in[4];
  const float* b1  = (const float*)d_in[5];
  const float* W2  = (const float*)d_in[6];
  const float* as2 = (const float*)d_in[7];
  const float* ad2 = (const float*)d_in[8];
  const float* b2  = (const float*)d_in[9];
  float* out = (float*)d_out;

  // workspace carve. h2f8 aliases h1f8 (h1 dead after attn1).
  // hist (12.8 MB) aliases helu (hist dead after scatter2; attn1 writes helu).
  char* p = (char*)d_ws;
  unsigned char* h1f8 = (unsigned char*)p; p += (size_t)N * 128;
  unsigned char* h2f8 = h1f8;                      // alias, [N][64]
  unsigned short* helu = (unsigned short*)p; p += (size_t)NCHUNK * N * 4;  // w/ hist
  int* hist = (int*)helu;
  unsigned short* Wt1  = (unsigned short*)p; p += (size_t)128 * 256 * 2;
  unsigned short* Wt2  = (unsigned short*)p; p += (size_t)64 * 128 * 2;
  float* als1 = (float*)p; p += (size_t)N * 8 * 4;
  float* ald1 = (float*)p; p += (size_t)N * 8 * 4;
  float* als2 = (float*)p; p += (size_t)N * 4;
  float* ald2 = (float*)p; p += (size_t)N * 4;
  int* deg     = (int*)p; p += (size_t)N * 4;
  int* rowptr  = (int*)p; p += (size_t)(N + 1) * 4;
  int* bsum    = (int*)p; p += 64 * 4;
  int* csr_src = (int*)p; p += (size_t)ET * 4;

  convw_kernel<<<(128 * 256 + 64 * 128 + 255) / 256, 256, 0, stream>>>(W1, W2, Wt1, Wt2);

  hist_kernel<<<NCHUNK * NRANGE, 512, 0, stream>>>(ei, hist, E, N, ET, CS);
  colscan_kernel<<<(N + 255) / 256, 256, 0, stream>>>(hist, deg, N);
  scan1_kernel<<<NB, 1024, 0, stream>>>(deg, rowptr, bsum, N);
  scan2_kernel<<<1, 64, 0, stream>>>(bsum, NB);
  scan3_kernel<<<(N + 256) / 256, 256, 0, stream>>>(rowptr, bsum, N, ET);
  scatter2_kernel<<<NCHUNK * NRANGE, 512, 0, stream>>>(ei, hist, rowptr, csr_src, E, N, ET, CS);

  gemm1_mfma<<<(N + 63) / 64, 256, 0, stream>>>(x, Wt1, h1f8, N);
  dots1_kernel<<<(N + 3) / 4, 256, 0, stream>>>(h1f8, as1, ad1, als1, ald1, N);
  attn1_kernel<<<(N + 3) / 4, 256, 0, stream>>>(h1f8, als1, ald1, b1, rowptr, csr_src, helu, N);

  gemm2_mfma<<<(N + 63) / 64, 256, 0, stream>>>(helu, Wt2, h2f8, N);
  dots2_kernel<<<(N + 3) / 4, 256, 0, stream>>>(h2f8, as2, ad2, als2, ald2, N);
  attn2_kernel<<<(N + 3) / 4, 256, 0, stream>>>(h2f8, als2, ald2, b2, rowptr, csr_src, out, N);
}

// Round 9
// 253.794 us; speedup vs baseline: 1.1684x; 1.0489x over previous
//
#include <hip/hip_runtime.h>
#include <hip/hip_bf16.h>

// ---------------------------------------------------------------------------
// GAT 2-layer forward on MI355X.
//   CSR build via atomic-free counting sort (LDS histograms + scans);
//   convw fused into hist (block-range split), scan2 fused into scan3.
//   GEMMs: bf16 MFMA 16x16x32, A prefetched in registers, B staged in LDS;
//   attention-logit dot products (dots1/dots2) fused into GEMM epilogues
//   via width-16 shuffle allreduce (als from fp32 acc: more accurate).
//   h1/h2 stored FP8 e4m3 (halves gather bytes; h2 L2-resident).
//   Attention: phase-split waves + quad-unrolled gathers, single-pass
//   softmax (logits bounded).
// ---------------------------------------------------------------------------

typedef __attribute__((ext_vector_type(8))) short short8;
typedef __attribute__((ext_vector_type(4))) float f4;
typedef __attribute__((ext_vector_type(2))) float float2v;

#define NCHUNK 64      // edge chunks
#define NRANGE 4       // node ranges
#define RSIZE 16384    // nodes per range (64 KB LDS histogram)
#define G1PAD 136      // LDS row stride (shorts) for B tiles
#define G2PAD 136
#define CONVB 80       // extra blocks in hist grid doing weight transpose

__device__ __forceinline__ unsigned short f2bf(float f) {
  unsigned int u = __builtin_bit_cast(unsigned int, f);
  u += 0x7fffu + ((u >> 16) & 1u);             // round-nearest-even
  return (unsigned short)(u >> 16);
}
__device__ __forceinline__ float bf2f(unsigned short h) {
  unsigned int u = ((unsigned int)h) << 16;
  return __builtin_bit_cast(float, u);
}

// float -> fp8 e4m3fn, RNE, saturating (software; used in GEMM epilogues)
__device__ __forceinline__ unsigned char f2fp8(float f) {
  unsigned int u = __builtin_bit_cast(unsigned int, f);
  unsigned int s = (u >> 24) & 0x80u;
  float a = fabsf(f);
  a = fminf(a, 448.f);
  if (a < 0.015625f) {                  // subnormal: step 2^-9
    int m = (int)rintf(a * 512.f);
    return (unsigned char)(s | (unsigned)m);
  }
  unsigned int ub = __builtin_bit_cast(unsigned int, a);
  ub += 0xFFFFFu + ((ub >> 20) & 1u);   // RNE into 3-bit mantissa
  unsigned int e = (ub >> 23) - 120u;
  unsigned int m = (ub >> 20) & 7u;
  if (e > 15u) { e = 15u; m = 6u; }     // clamp to 448
  return (unsigned char)(s | (e << 3) | m);
}

// --------------- CSR pass 1 (+ fused weight transpose blocks) -------------
__global__ __launch_bounds__(512) void hist_kernel(const int* __restrict__ ei,
                                                   int* __restrict__ hist,
                                                   const float* __restrict__ W1,
                                                   const float* __restrict__ W2,
                                                   unsigned short* __restrict__ Wt1,
                                                   unsigned short* __restrict__ Wt2,
                                                   int E, int N, int ET, int CS) {
  if (blockIdx.x >= NCHUNK * NRANGE) {           // convw blocks (block-uniform)
    int i = (blockIdx.x - NCHUNK * NRANGE) * 512 + threadIdx.x;
    if (i < 128 * 256) {
      int n = i >> 8, k = i & 255;
      Wt1[i] = f2bf(W1[k * 128 + n]);
    } else {
      int j = i - 128 * 256;
      if (j < 64 * 128) {
        int n = j >> 7, k = j & 127;
        Wt2[j] = f2bf(W2[k * 64 + n]);
      }
    }
    return;
  }
  __shared__ int lh[RSIZE];
  const int c = blockIdx.x & (NCHUNK - 1);
  const int r = blockIdx.x >> 6;
  const int base = r * RSIZE;
  for (int i = threadIdx.x; i < RSIZE; i += 512) lh[i] = 0;
  __syncthreads();
  const int e0 = c * CS, e1 = min(e0 + CS, ET);
  for (int e = e0 + threadIdx.x; e < e1; e += 512) {
    int d = (e < E) ? ei[E + e] : (e - E);
    unsigned dl = (unsigned)(d - base);
    if (dl < RSIZE) atomicAdd(&lh[dl], 1);
  }
  __syncthreads();
  for (int i = threadIdx.x; i < RSIZE; i += 512) {
    int d = base + i;
    if (d < N) hist[c * N + d] = lh[i];
  }
}

__global__ __launch_bounds__(256) void colscan_kernel(int* __restrict__ hist,
                                                      int* __restrict__ deg, int N) {
  int d = blockIdx.x * 256 + threadIdx.x;
  if (d >= N) return;
  int run = 0;
#pragma unroll 8
  for (int c = 0; c < NCHUNK; ++c) {
    int v = hist[c * N + d];
    hist[c * N + d] = run;
    run += v;
  }
  deg[d] = run;
}

__global__ __launch_bounds__(1024) void scan1_kernel(const int* __restrict__ deg,
                                                     int* __restrict__ rowptr,
                                                     int* __restrict__ bsum, int N) {
  __shared__ int wtot[16];
  const int lane = threadIdx.x & 63, wid = threadIdx.x >> 6;
  int i = blockIdx.x * 1024 + threadIdx.x;
  int v = (i < N) ? deg[i] : 0;
  int incl = v;
#pragma unroll
  for (int off = 1; off < 64; off <<= 1) {
    int t = __shfl_up(incl, off, 64);
    if (lane >= off) incl += t;
  }
  if (lane == 63) wtot[wid] = incl;
  __syncthreads();
  int woff = 0;
#pragma unroll
  for (int w = 0; w < 16; ++w) woff += (w < wid) ? wtot[w] : 0;
  if (i < N) rowptr[i] = woff + incl - v;
  if (threadIdx.x == 1023) bsum[blockIdx.x] = woff + incl;   // raw block total
}

// scan3 with fused bsum prefix (scan2 eliminated): each block reduces the
// <=49 raw block totals below its 1024-group in one 64-lane shuffle.
__global__ __launch_bounds__(256) void scan3_kernel(int* __restrict__ rowptr,
                                                    const int* __restrict__ bsum,
                                                    int N, int ET) {
  int lane = threadIdx.x & 63;
  int g = blockIdx.x >> 2;                 // 1024-group index
  int bv = (lane < g) ? bsum[lane] : 0;
#pragma unroll
  for (int off = 32; off; off >>= 1) bv += __shfl_xor(bv, off, 64);
  int i = blockIdx.x * 256 + threadIdx.x;
  if (i < N) rowptr[i] += bv;
  if (i == N) rowptr[N] = ET;
}

__global__ __launch_bounds__(512) void scatter2_kernel(const int* __restrict__ ei,
                                                       const int* __restrict__ hist,
                                                       const int* __restrict__ rowptr,
                                                       int* __restrict__ csr_src,
                                                       int E, int N, int ET, int CS) {
  __shared__ int lh[RSIZE];
  const int c = blockIdx.x & (NCHUNK - 1);
  const int r = blockIdx.x >> 6;
  const int base = r * RSIZE;
  for (int i = threadIdx.x; i < RSIZE; i += 512) {
    int d = base + i;
    lh[i] = (d < N) ? (rowptr[d] + hist[c * N + d]) : 0;
  }
  __syncthreads();
  const int e0 = c * CS, e1 = min(e0 + CS, ET);
  for (int e = e0 + threadIdx.x; e < e1; e += 512) {
    int s, d;
    if (e < E) { s = ei[e]; d = ei[E + e]; }
    else       { s = e - E; d = s; }
    unsigned dl = (unsigned)(d - base);
    if (dl < RSIZE) {
      int slot = atomicAdd(&lh[dl], 1);
      csr_src[slot] = s;
    }
  }
}

// ---------------------- GEMM1 (MFMA, fused dots1) -------------------------
// H1f8[M,128] = fp8( X[M,256] @ W1 );  als1/ald1 from fp32 acc (head = b).
__global__ __launch_bounds__(256, 3) void gemm1_mfma(const float* __restrict__ X,
                                                     const unsigned short* __restrict__ Wt,
                                                     const float* __restrict__ as1,
                                                     const float* __restrict__ ad1,
                                                     unsigned char* __restrict__ H,
                                                     float* __restrict__ als,
                                                     float* __restrict__ ald,
                                                     int M) {
  __shared__ unsigned short bl[128 * G1PAD];
  const int t = threadIdx.x;
  const int wv = t >> 6, ln = t & 63;
  const int ml = ln & 15, q = ln >> 4;
  const int r0 = blockIdx.x * 64 + wv * 16;
  const int arow = min(r0 + ml, M - 1);
  const float* xp = X + (size_t)arow * 256 + q * 8;

  float4 a0[8], a1[8];
#pragma unroll
  for (int s = 0; s < 8; ++s) {
    a0[s] = *(const float4*)(xp + s * 32);
    a1[s] = *(const float4*)(xp + s * 32 + 4);
  }

  f4 acc[8];
#pragma unroll
  for (int b = 0; b < 8; ++b) acc[b] = (f4)0.f;

  const int crow = t >> 1, coff = (t & 1) * 64;
#pragma unroll
  for (int half = 0; half < 2; ++half) {
    __syncthreads();
    {
      const unsigned short* src = Wt + (size_t)crow * 256 + half * 128 + coff;
      unsigned short* dst = &bl[crow * G1PAD + coff];
#pragma unroll
      for (int c = 0; c < 8; ++c)
        *(short8*)(dst + c * 8) = *(const short8*)(src + c * 8);
    }
    __syncthreads();
#pragma unroll
    for (int sl = 0; sl < 4; ++sl) {
      const int s = half * 4 + sl;
      short8 av;
      av[0] = (short)f2bf(a0[s].x); av[1] = (short)f2bf(a0[s].y);
      av[2] = (short)f2bf(a0[s].z); av[3] = (short)f2bf(a0[s].w);
      av[4] = (short)f2bf(a1[s].x); av[5] = (short)f2bf(a1[s].y);
      av[6] = (short)f2bf(a1[s].z); av[7] = (short)f2bf(a1[s].w);
#pragma unroll
      for (int b = 0; b < 8; ++b) {
        short8 bfr = *(const short8*)&bl[(b * 16 + ml) * G1PAD + sl * 32 + q * 8];
        acc[b] = __builtin_amdgcn_mfma_f32_16x16x32_bf16(av, bfr, acc[b], 0, 0, 0);
      }
    }
  }

  // epilogue: fp8 store + fused dots (als/ald), head h = b, reduce over ml
#pragma unroll
  for (int i = 0; i < 4; ++i) {
    int rr = r0 + q * 4 + i;
    bool ok = rr < M;
    if (ok) {
#pragma unroll
      for (int b = 0; b < 8; ++b)
        H[(size_t)rr * 128 + b * 16 + ml] = f2fp8(acc[b][i]);
    }
#pragma unroll
    for (int b = 0; b < 8; ++b) {
      float ps = acc[b][i] * as1[b * 16 + ml];
      float pd = acc[b][i] * ad1[b * 16 + ml];
#pragma unroll
      for (int off = 1; off < 16; off <<= 1) {
        ps += __shfl_xor(ps, off, 16);
        pd += __shfl_xor(pd, off, 16);
      }
      if (ok && ml == b) {               // lane b of the group stores head b
        als[(size_t)rr * 8 + b] = ps;
        ald[(size_t)rr * 8 + b] = pd;
      }
    }
  }
}

// ---------------------- GEMM2 (MFMA, fused dots2) -------------------------
// H2f8[M,64] = fp8( helu[M,128](bf16) @ W2 );  als2/ald2 from fp32 acc.
__global__ __launch_bounds__(256, 4) void gemm2_mfma(const unsigned short* __restrict__ Xb,
                                                     const unsigned short* __restrict__ Wt,
                                                     const float* __restrict__ as2,
                                                     const float* __restrict__ ad2,
                                                     unsigned char* __restrict__ H,
                                                     float* __restrict__ als,
                                                     float* __restrict__ ald,
                                                     int M) {
  __shared__ unsigned short bl[64 * G2PAD];
  const int t = threadIdx.x;
  const int wv = t >> 6, ln = t & 63;
  const int ml = ln & 15, q = ln >> 4;
  const int r0 = blockIdx.x * 64 + wv * 16;
  const int arow = min(r0 + ml, M - 1);
  const unsigned short* xp = Xb + (size_t)arow * 128 + q * 8;

  short8 av[4];
#pragma unroll
  for (int s = 0; s < 4; ++s) av[s] = *(const short8*)(xp + s * 32);

  {
    const int crow = t >> 2, coff = (t & 3) * 32;
    const unsigned short* src = Wt + (size_t)crow * 128 + coff;
    unsigned short* dst = &bl[crow * G2PAD + coff];
#pragma unroll
    for (int c = 0; c < 4; ++c)
      *(short8*)(dst + c * 8) = *(const short8*)(src + c * 8);
  }
  __syncthreads();

  f4 acc[4];
#pragma unroll
  for (int b = 0; b < 4; ++b) acc[b] = (f4)0.f;

#pragma unroll
  for (int s = 0; s < 4; ++s) {
#pragma unroll
    for (int b = 0; b < 4; ++b) {
      short8 bfr = *(const short8*)&bl[(b * 16 + ml) * G2PAD + s * 32 + q * 8];
      acc[b] = __builtin_amdgcn_mfma_f32_16x16x32_bf16(av[s], bfr, acc[b], 0, 0, 0);
    }
  }

#pragma unroll
  for (int i = 0; i < 4; ++i) {
    int rr = r0 + q * 4 + i;
    bool ok = rr < M;
    if (ok) {
#pragma unroll
      for (int b = 0; b < 4; ++b)
        H[(size_t)rr * 64 + b * 16 + ml] = f2fp8(acc[b][i]);
    }
    float ps = 0.f, pd = 0.f;
#pragma unroll
    for (int b = 0; b < 4; ++b) {
      ps += acc[b][i] * as2[b * 16 + ml];
      pd += acc[b][i] * ad2[b * 16 + ml];
    }
#pragma unroll
    for (int off = 1; off < 16; off <<= 1) {
      ps += __shfl_xor(ps, off, 16);
      pd += __shfl_xor(pd, off, 16);
    }
    if (ok && ml == 0) { als[rr] = ps; ald[rr] = pd; }
  }
}

// ------------------------------- attn1 ------------------------------------
// one wave per dst. Phase 1 per 8-edge batch: lane (e=l>>3, h=l&7) computes
// one distinct weight. Phase 2: shuffle w/src, gather fp8 pair (cols 2l,2l+1),
// decode with one v_cvt_pk_f32_fp8, accumulate. Tail lanes contribute 0.0f.
__global__ __launch_bounds__(256) void attn1_kernel(
    const unsigned char* __restrict__ h1, const float* __restrict__ als,
    const float* __restrict__ ald, const float* __restrict__ b1,
    const int* __restrict__ rowptr, const int* __restrict__ csr_src,
    unsigned short* __restrict__ helu, int N) {
  int d = __builtin_amdgcn_readfirstlane(
      (blockIdx.x * blockDim.x + threadIdx.x) >> 6);
  int lane = threadIdx.x & 63;
  if (d >= N) return;
  const int hh = lane >> 3;            // phase-2 head (feature pair 2l,2l+1)
  const int hw = lane & 7;             // phase-1 head
  const int ew = lane >> 3;            // phase-1 edge-in-batch
  const float aldp = ald[d * 8 + hw];
  const int beg = rowptr[d], end = rowptr[d + 1];
  const unsigned char* h1l = h1 + 2 * lane;
  float den = 0.f, ax = 0.f, ay = 0.f;

  for (int p0 = beg; p0 < end; p0 += 8) {
    int idx = p0 + ew;
    int se = csr_src[idx < end ? idx : end - 1];
    float v = als[se * 8 + hw] + aldp;
    v = fmaxf(v, 0.2f * v);                      // leaky_relu
    float w = (idx < end) ? __expf(v) : 0.f;
#pragma unroll
    for (int j = 0; j < 4; ++j) {
      float wj = __shfl(w, j * 8 + hh);
      int sj = __shfl(se, j * 8);
      unsigned short pk = *(const unsigned short*)(h1l + (size_t)sj * 128);
      float2v g = __builtin_amdgcn_cvt_pk_f32_fp8(pk, false);
      den += wj; ax += wj * g.x; ay += wj * g.y;
    }
    if (p0 + 4 < end) {
#pragma unroll
      for (int j = 4; j < 8; ++j) {
        float wj = __shfl(w, j * 8 + hh);
        int sj = __shfl(se, j * 8);
        unsigned short pk = *(const unsigned short*)(h1l + (size_t)sj * 128);
        float2v g = __builtin_amdgcn_cvt_pk_f32_fp8(pk, false);
        den += wj; ax += wj * g.x; ay += wj * g.y;
      }
    }
  }

  float inv = 1.0f / (den + 1e-16f);
  float2 bb = *(const float2*)(b1 + 2 * lane);
  float o0 = ax * inv + bb.x;
  float o1 = ay * inv + bb.y;
  o0 = o0 > 0.f ? o0 : __expf(o0) - 1.0f;        // ELU
  o1 = o1 > 0.f ? o1 : __expf(o1) - 1.0f;
  ushort2 ov; ov.x = f2bf(o0); ov.y = f2bf(o1);
  *(ushort2*)(helu + (size_t)d * 128 + 2 * lane) = ov;
}

// ------------------------------- attn2 ------------------------------------
__global__ __launch_bounds__(256) void attn2_kernel(
    const unsigned char* __restrict__ h2, const float* __restrict__ als,
    const float* __restrict__ ald, const float* __restrict__ b2,
    const int* __restrict__ rowptr, const int* __restrict__ csr_src,
    float* __restrict__ out, int N) {
  int d = __builtin_amdgcn_readfirstlane(
      (blockIdx.x * blockDim.x + threadIdx.x) >> 6);
  int lane = threadIdx.x & 63;
  if (d >= N) return;
  const float aldd = ald[d];
  const int beg = rowptr[d], end = rowptr[d + 1];
  const unsigned char* h2l = h2 + lane;
  float den = 0.f, acc = 0.f;

  for (int p0 = beg; p0 < end; p0 += 64) {
    int idx = p0 + lane;
    int se = csr_src[idx < end ? idx : end - 1];
    float v = als[se] + aldd;
    v = fmaxf(v, 0.2f * v);
    float w = (idx < end) ? __expf(v) : 0.f;
    int cnt = min(64, end - p0);
    for (int j0 = 0; j0 < cnt; j0 += 4) {
#pragma unroll
      for (int j = 0; j < 4; ++j) {
        float wj = __shfl(w, j0 + j);
        int sj = __shfl(se, j0 + j);
        float g = __builtin_amdgcn_cvt_f32_fp8(h2l[(size_t)sj * 64], 0);
        den += wj; acc += wj * g;
      }
    }
  }

  float z = acc / (den + 1e-16f) + b2[lane];
  float zm = z;
#pragma unroll
  for (int off = 32; off; off >>= 1) zm = fmaxf(zm, __shfl_xor(zm, off, 64));
  float ex = __expf(z - zm), se2 = ex;
#pragma unroll
  for (int off = 32; off; off >>= 1) se2 += __shfl_xor(se2, off, 64);
  out[(size_t)d * 64 + lane] = z - zm - __logf(se2);
}

// ------------------------------- launch -----------------------------------
extern "C" void kernel_launch(void* const* d_in, const int* in_sizes, int n_in,
                              void* d_out, int out_size, void* d_ws, size_t ws_size,
                              hipStream_t stream) {
  const int N = in_sizes[0] / 256;   // 50000
  const int E = in_sizes[1] / 2;     // 800000
  const int ET = E + N;
  const int CS = (ET + NCHUNK - 1) / NCHUNK;
  const int NB = (N + 1023) / 1024;

  const float* x   = (const float*)d_in[0];
  const int*   ei  = (const int*)d_in[1];
  const float* W1  = (const float*)d_in[2];
  const float* as1 = (const float*)d_in[3];
  const float* ad1 = (const float*)d_in[4];
  const float* b1  = (const float*)d_in[5];
  const float* W2  = (const float*)d_in[6];
  const float* as2 = (const float*)d_in[7];
  const float* ad2 = (const float*)d_in[8];
  const float* b2  = (const float*)d_in[9];
  float* out = (float*)d_out;

  // workspace carve. h2f8 aliases h1f8 (h1 dead after attn1).
  // hist (12.8 MB) aliases helu (hist dead after scatter2; attn1 writes helu).
  char* p = (char*)d_ws;
  unsigned char* h1f8 = (unsigned char*)p; p += (size_t)N * 128;
  unsigned char* h2f8 = h1f8;                      // alias, [N][64]
  unsigned short* helu = (unsigned short*)p; p += (size_t)NCHUNK * N * 4;  // w/ hist
  int* hist = (int*)helu;
  unsigned short* Wt1  = (unsigned short*)p; p += (size_t)128 * 256 * 2;
  unsigned short* Wt2  = (unsigned short*)p; p += (size_t)64 * 128 * 2;
  float* als1 = (float*)p; p += (size_t)N * 8 * 4;
  float* ald1 = (float*)p; p += (size_t)N * 8 * 4;
  float* als2 = (float*)p; p += (size_t)N * 4;
  float* ald2 = (float*)p; p += (size_t)N * 4;
  int* deg     = (int*)p; p += (size_t)N * 4;
  int* rowptr  = (int*)p; p += (size_t)(N + 1) * 4;
  int* bsum    = (int*)p; p += 64 * 4;
  int* csr_src = (int*)p; p += (size_t)ET * 4;

  hist_kernel<<<NCHUNK * NRANGE + CONVB, 512, 0, stream>>>(ei, hist, W1, W2, Wt1, Wt2,
                                                           E, N, ET, CS);
  colscan_kernel<<<(N + 255) / 256, 256, 0, stream>>>(hist, deg, N);
  scan1_kernel<<<NB, 1024, 0, stream>>>(deg, rowptr, bsum, N);
  scan3_kernel<<<(N + 256) / 256, 256, 0, stream>>>(rowptr, bsum, N, ET);
  scatter2_kernel<<<NCHUNK * NRANGE, 512, 0, stream>>>(ei, hist, rowptr, csr_src, E, N, ET, CS);

  gemm1_mfma<<<(N + 63) / 64, 256, 0, stream>>>(x, Wt1, as1, ad1, h1f8, als1, ald1, N);
  attn1_kernel<<<(N + 3) / 4, 256, 0, stream>>>(h1f8, als1, ald1, b1, rowptr, csr_src, helu, N);

  gemm2_mfma<<<(N + 63) / 64, 256, 0, stream>>>(helu, Wt2, as2, ad2, h2f8, als2, ald2, N);
  attn2_kernel<<<(N + 3) / 4, 256, 0, stream>>>(h2f8, als2, ald2, b2, rowptr, csr_src, out, N);
}

// Round 12
// 252.726 us; speedup vs baseline: 1.1733x; 1.0042x over previous
//
#include <hip/hip_runtime.h>
#include <hip/hip_bf16.h>

// ---------------------------------------------------------------------------
// GAT 2-layer forward on MI355X.
//   CSR build via atomic-free counting sort (LDS histograms + scans);
//   convw fused into hist, scan2 fused into scan3.
//   GEMM1: bf16 MFMA, N split into two 64-col halves -> 2x blocks
//   (R9 showed 25% occupancy / grid-limited TLP was the binding constraint).
//   dots fused into GEMM epilogues (als/ald from fp32 acc).
//   h1/h2 stored FP8 e4m3 (halves gather bytes; h2 L2-resident).
//   Attention: phase-split waves + quad-unrolled gathers, single-pass
//   softmax (logits bounded).
// ---------------------------------------------------------------------------

typedef __attribute__((ext_vector_type(8))) short short8;
typedef __attribute__((ext_vector_type(4))) float f4;
typedef __attribute__((ext_vector_type(2))) float float2v;

#define NCHUNK 64      // edge chunks
#define NRANGE 4       // node ranges
#define RSIZE 16384    // nodes per range (64 KB LDS histogram)
#define G1PAD 136      // LDS row stride (shorts) for B tiles
#define G2PAD 136
#define CONVB 80       // extra blocks in hist grid doing weight transpose

__device__ __forceinline__ unsigned short f2bf(float f) {
  unsigned int u = __builtin_bit_cast(unsigned int, f);
  u += 0x7fffu + ((u >> 16) & 1u);             // round-nearest-even
  return (unsigned short)(u >> 16);
}
__device__ __forceinline__ float bf2f(unsigned short h) {
  unsigned int u = ((unsigned int)h) << 16;
  return __builtin_bit_cast(float, u);
}

// float -> fp8 e4m3fn, RNE, saturating (software; used in GEMM epilogues)
__device__ __forceinline__ unsigned char f2fp8(float f) {
  unsigned int u = __builtin_bit_cast(unsigned int, f);
  unsigned int s = (u >> 24) & 0x80u;
  float a = fabsf(f);
  a = fminf(a, 448.f);
  if (a < 0.015625f) {                  // subnormal: step 2^-9
    int m = (int)rintf(a * 512.f);
    return (unsigned char)(s | (unsigned)m);
  }
  unsigned int ub = __builtin_bit_cast(unsigned int, a);
  ub += 0xFFFFFu + ((ub >> 20) & 1u);   // RNE into 3-bit mantissa
  unsigned int e = (ub >> 23) - 120u;
  unsigned int m = (ub >> 20) & 7u;
  if (e > 15u) { e = 15u; m = 6u; }     // clamp to 448
  return (unsigned char)(s | (e << 3) | m);
}

// --------------- CSR pass 1 (+ fused weight transpose blocks) -------------
__global__ __launch_bounds__(512) void hist_kernel(const int* __restrict__ ei,
                                                   int* __restrict__ hist,
                                                   const float* __restrict__ W1,
                                                   const float* __restrict__ W2,
                                                   unsigned short* __restrict__ Wt1,
                                                   unsigned short* __restrict__ Wt2,
                                                   int E, int N, int ET, int CS) {
  if (blockIdx.x >= NCHUNK * NRANGE) {           // convw blocks (block-uniform)
    int i = (blockIdx.x - NCHUNK * NRANGE) * 512 + threadIdx.x;
    if (i < 128 * 256) {
      int n = i >> 8, k = i & 255;
      Wt1[i] = f2bf(W1[k * 128 + n]);
    } else {
      int j = i - 128 * 256;
      if (j < 64 * 128) {
        int n = j >> 7, k = j & 127;
        Wt2[j] = f2bf(W2[k * 64 + n]);
      }
    }
    return;
  }
  __shared__ int lh[RSIZE];
  const int c = blockIdx.x & (NCHUNK - 1);
  const int r = blockIdx.x >> 6;
  const int base = r * RSIZE;
  for (int i = threadIdx.x; i < RSIZE; i += 512) lh[i] = 0;
  __syncthreads();
  const int e0 = c * CS, e1 = min(e0 + CS, ET);
  for (int e = e0 + threadIdx.x; e < e1; e += 512) {
    int d = (e < E) ? ei[E + e] : (e - E);
    unsigned dl = (unsigned)(d - base);
    if (dl < RSIZE) atomicAdd(&lh[dl], 1);
  }
  __syncthreads();
  for (int i = threadIdx.x; i < RSIZE; i += 512) {
    int d = base + i;
    if (d < N) hist[c * N + d] = lh[i];
  }
}

__global__ __launch_bounds__(256) void colscan_kernel(int* __restrict__ hist,
                                                      int* __restrict__ deg, int N) {
  int d = blockIdx.x * 256 + threadIdx.x;
  if (d >= N) return;
  int run = 0;
#pragma unroll 8
  for (int c = 0; c < NCHUNK; ++c) {
    int v = hist[c * N + d];
    hist[c * N + d] = run;
    run += v;
  }
  deg[d] = run;
}

__global__ __launch_bounds__(1024) void scan1_kernel(const int* __restrict__ deg,
                                                     int* __restrict__ rowptr,
                                                     int* __restrict__ bsum, int N) {
  __shared__ int wtot[16];
  const int lane = threadIdx.x & 63, wid = threadIdx.x >> 6;
  int i = blockIdx.x * 1024 + threadIdx.x;
  int v = (i < N) ? deg[i] : 0;
  int incl = v;
#pragma unroll
  for (int off = 1; off < 64; off <<= 1) {
    int t = __shfl_up(incl, off, 64);
    if (lane >= off) incl += t;
  }
  if (lane == 63) wtot[wid] = incl;
  __syncthreads();
  int woff = 0;
#pragma unroll
  for (int w = 0; w < 16; ++w) woff += (w < wid) ? wtot[w] : 0;
  if (i < N) rowptr[i] = woff + incl - v;
  if (threadIdx.x == 1023) bsum[blockIdx.x] = woff + incl;   // raw block total
}

// scan3 with fused bsum prefix: each block reduces the <=49 raw block totals
// below its 1024-group in one 64-lane shuffle.
__global__ __launch_bounds__(256) void scan3_kernel(int* __restrict__ rowptr,
                                                    const int* __restrict__ bsum,
                                                    int N, int ET) {
  int lane = threadIdx.x & 63;
  int g = blockIdx.x >> 2;                 // 1024-group index
  int bv = (lane < g) ? bsum[lane] : 0;
#pragma unroll
  for (int off = 32; off; off >>= 1) bv += __shfl_xor(bv, off, 64);
  int i = blockIdx.x * 256 + threadIdx.x;
  if (i < N) rowptr[i] += bv;
  if (i == N) rowptr[N] = ET;
}

__global__ __launch_bounds__(512) void scatter2_kernel(const int* __restrict__ ei,
                                                       const int* __restrict__ hist,
                                                       const int* __restrict__ rowptr,
                                                       int* __restrict__ csr_src,
                                                       int E, int N, int ET, int CS) {
  __shared__ int lh[RSIZE];
  const int c = blockIdx.x & (NCHUNK - 1);
  const int r = blockIdx.x >> 6;
  const int base = r * RSIZE;
  for (int i = threadIdx.x; i < RSIZE; i += 512) {
    int d = base + i;
    lh[i] = (d < N) ? (rowptr[d] + hist[c * N + d]) : 0;
  }
  __syncthreads();
  const int e0 = c * CS, e1 = min(e0 + CS, ET);
  for (int e = e0 + threadIdx.x; e < e1; e += 512) {
    int s, d;
    if (e < E) { s = ei[e]; d = ei[E + e]; }
    else       { s = e - E; d = s; }
    unsigned dl = (unsigned)(d - base);
    if (dl < RSIZE) {
      int slot = atomicAdd(&lh[dl], 1);
      csr_src[slot] = s;
    }
  }
}

// ---------------- GEMM1 (MFMA, N-split for occupancy, fused dots1) --------
// H1f8[M,128] = fp8( X[M,256] @ W1 );  als1/ald1 from fp32 acc.
// blockIdx bit0 = column half (64 cols); 2x blocks vs R9 -> ~24 waves/CU.
// A-loads are per-K-step (no prefetch array) -> low VGPR, no min-waves hint.
__global__ __launch_bounds__(256) void gemm1_mfma(const float* __restrict__ X,
                                                  const unsigned short* __restrict__ Wt,
                                                  const float* __restrict__ as1,
                                                  const float* __restrict__ ad1,
                                                  unsigned char* __restrict__ H,
                                                  float* __restrict__ als,
                                                  float* __restrict__ ald,
                                                  int M) {
  __shared__ unsigned short bl[64 * G1PAD];
  const int t = threadIdx.x;
  const int wv = t >> 6, ln = t & 63;
  const int ml = ln & 15, q = ln >> 4;
  const int ch = blockIdx.x & 1;                    // column half
  const int r0 = (blockIdx.x >> 1) * 64 + wv * 16;
  const int arow = min(r0 + ml, M - 1);
  const float* xp = X + (size_t)arow * 256 + q * 8;

  f4 acc[4];
#pragma unroll
  for (int b = 0; b < 4; ++b) acc[b] = (f4)0.f;

  const int crow = t >> 2, koff = (t & 3) * 32;
  const unsigned short* wsrc = Wt + (size_t)(ch * 64 + crow) * 256 + koff;

#pragma unroll
  for (int half = 0; half < 2; ++half) {
    __syncthreads();
    {
      const unsigned short* src = wsrc + half * 128;
      unsigned short* dst = &bl[crow * G1PAD + koff];
#pragma unroll
      for (int c = 0; c < 4; ++c)
        *(short8*)(dst + c * 8) = *(const short8*)(src + c * 8);
    }
    __syncthreads();
#pragma unroll
    for (int sl = 0; sl < 4; ++sl) {
      const int s = half * 4 + sl;
      float4 a0 = *(const float4*)(xp + s * 32);
      float4 a1 = *(const float4*)(xp + s * 32 + 4);
      short8 av;
      av[0] = (short)f2bf(a0.x); av[1] = (short)f2bf(a0.y);
      av[2] = (short)f2bf(a0.z); av[3] = (short)f2bf(a0.w);
      av[4] = (short)f2bf(a1.x); av[5] = (short)f2bf(a1.y);
      av[6] = (short)f2bf(a1.z); av[7] = (short)f2bf(a1.w);
#pragma unroll
      for (int b = 0; b < 4; ++b) {
        short8 bfr = *(const short8*)&bl[(b * 16 + ml) * G1PAD + sl * 32 + q * 8];
        acc[b] = __builtin_amdgcn_mfma_f32_16x16x32_bf16(av, bfr, acc[b], 0, 0, 0);
      }
    }
  }

  // epilogue: fp8 store + fused dots, head = ch*4+b, reduce over ml (dim)
#pragma unroll
  for (int i = 0; i < 4; ++i) {
    int rr = r0 + q * 4 + i;
    bool ok = rr < M;
    if (ok) {
#pragma unroll
      for (int b = 0; b < 4; ++b)
        H[(size_t)rr * 128 + ch * 64 + b * 16 + ml] = f2fp8(acc[b][i]);
    }
#pragma unroll
    for (int b = 0; b < 4; ++b) {
      float ps = acc[b][i] * as1[ch * 64 + b * 16 + ml];
      float pd = acc[b][i] * ad1[ch * 64 + b * 16 + ml];
#pragma unroll
      for (int off = 1; off < 16; off <<= 1) {
        ps += __shfl_xor(ps, off, 16);
        pd += __shfl_xor(pd, off, 16);
      }
      if (ok && ml == b) {               // lane b of the group stores its head
        als[(size_t)rr * 8 + ch * 4 + b] = ps;
        ald[(size_t)rr * 8 + ch * 4 + b] = pd;
      }
    }
  }
}

// ---------------------- GEMM2 (MFMA, fused dots2) -------------------------
// H2f8[M,64] = fp8( helu[M,128](bf16) @ W2 );  als2/ald2 from fp32 acc.
__global__ __launch_bounds__(256) void gemm2_mfma(const unsigned short* __restrict__ Xb,
                                                  const unsigned short* __restrict__ Wt,
                                                  const float* __restrict__ as2,
                                                  const float* __restrict__ ad2,
                                                  unsigned char* __restrict__ H,
                                                  float* __restrict__ als,
                                                  float* __restrict__ ald,
                                                  int M) {
  __shared__ unsigned short bl[64 * G2PAD];
  const int t = threadIdx.x;
  const int wv = t >> 6, ln = t & 63;
  const int ml = ln & 15, q = ln >> 4;
  const int r0 = blockIdx.x * 64 + wv * 16;
  const int arow = min(r0 + ml, M - 1);
  const unsigned short* xp = Xb + (size_t)arow * 128 + q * 8;

  short8 av[4];
#pragma unroll
  for (int s = 0; s < 4; ++s) av[s] = *(const short8*)(xp + s * 32);

  {
    const int crow = t >> 2, coff = (t & 3) * 32;
    const unsigned short* src = Wt + (size_t)crow * 128 + coff;
    unsigned short* dst = &bl[crow * G2PAD + coff];
#pragma unroll
    for (int c = 0; c < 4; ++c)
      *(short8*)(dst + c * 8) = *(const short8*)(src + c * 8);
  }
  __syncthreads();

  f4 acc[4];
#pragma unroll
  for (int b = 0; b < 4; ++b) acc[b] = (f4)0.f;

#pragma unroll
  for (int s = 0; s < 4; ++s) {
#pragma unroll
    for (int b = 0; b < 4; ++b) {
      short8 bfr = *(const short8*)&bl[(b * 16 + ml) * G2PAD + s * 32 + q * 8];
      acc[b] = __builtin_amdgcn_mfma_f32_16x16x32_bf16(av[s], bfr, acc[b], 0, 0, 0);
    }
  }

#pragma unroll
  for (int i = 0; i < 4; ++i) {
    int rr = r0 + q * 4 + i;
    bool ok = rr < M;
    if (ok) {
#pragma unroll
      for (int b = 0; b < 4; ++b)
        H[(size_t)rr * 64 + b * 16 + ml] = f2fp8(acc[b][i]);
    }
    float ps = 0.f, pd = 0.f;
#pragma unroll
    for (int b = 0; b < 4; ++b) {
      ps += acc[b][i] * as2[b * 16 + ml];
      pd += acc[b][i] * ad2[b * 16 + ml];
    }
#pragma unroll
    for (int off = 1; off < 16; off <<= 1) {
      ps += __shfl_xor(ps, off, 16);
      pd += __shfl_xor(pd, off, 16);
    }
    if (ok && ml == 0) { als[rr] = ps; ald[rr] = pd; }
  }
}

// ------------------------------- attn1 ------------------------------------
__global__ __launch_bounds__(256) void attn1_kernel(
    const unsigned char* __restrict__ h1, const float* __restrict__ als,
    const float* __restrict__ ald, const float* __restrict__ b1,
    const int* __restrict__ rowptr, const int* __restrict__ csr_src,
    unsigned short* __restrict__ helu, int N) {
  int d = __builtin_amdgcn_readfirstlane(
      (blockIdx.x * blockDim.x + threadIdx.x) >> 6);
  int lane = threadIdx.x & 63;
  if (d >= N) return;
  const int hh = lane >> 3;            // phase-2 head (feature pair 2l,2l+1)
  const int hw = lane & 7;             // phase-1 head
  const int ew = lane >> 3;            // phase-1 edge-in-batch
  const float aldp = ald[d * 8 + hw];
  const int beg = rowptr[d], end = rowptr[d + 1];
  const unsigned char* h1l = h1 + 2 * lane;
  float den = 0.f, ax = 0.f, ay = 0.f;

  for (int p0 = beg; p0 < end; p0 += 8) {
    int idx = p0 + ew;
    int se = csr_src[idx < end ? idx : end - 1];
    float v = als[se * 8 + hw] + aldp;
    v = fmaxf(v, 0.2f * v);                      // leaky_relu
    float w = (idx < end) ? __expf(v) : 0.f;
#pragma unroll
    for (int j = 0; j < 4; ++j) {
      float wj = __shfl(w, j * 8 + hh);
      int sj = __shfl(se, j * 8);
      unsigned short pk = *(const unsigned short*)(h1l + (size_t)sj * 128);
      float2v g = __builtin_amdgcn_cvt_pk_f32_fp8(pk, false);
      den += wj; ax += wj * g.x; ay += wj * g.y;
    }
    if (p0 + 4 < end) {
#pragma unroll
      for (int j = 4; j < 8; ++j) {
        float wj = __shfl(w, j * 8 + hh);
        int sj = __shfl(se, j * 8);
        unsigned short pk = *(const unsigned short*)(h1l + (size_t)sj * 128);
        float2v g = __builtin_amdgcn_cvt_pk_f32_fp8(pk, false);
        den += wj; ax += wj * g.x; ay += wj * g.y;
      }
    }
  }

  float inv = 1.0f / (den + 1e-16f);
  float2 bb = *(const float2*)(b1 + 2 * lane);
  float o0 = ax * inv + bb.x;
  float o1 = ay * inv + bb.y;
  o0 = o0 > 0.f ? o0 : __expf(o0) - 1.0f;        // ELU
  o1 = o1 > 0.f ? o1 : __expf(o1) - 1.0f;
  ushort2 ov; ov.x = f2bf(o0); ov.y = f2bf(o1);
  *(ushort2*)(helu + (size_t)d * 128 + 2 * lane) = ov;
}

// ------------------------------- attn2 ------------------------------------
__global__ __launch_bounds__(256) void attn2_kernel(
    const unsigned char* __restrict__ h2, const float* __restrict__ als,
    const float* __restrict__ ald, const float* __restrict__ b2,
    const int* __restrict__ rowptr, const int* __restrict__ csr_src,
    float* __restrict__ out, int N) {
  int d = __builtin_amdgcn_readfirstlane(
      (blockIdx.x * blockDim.x + threadIdx.x) >> 6);
  int lane = threadIdx.x & 63;
  if (d >= N) return;
  const float aldd = ald[d];
  const int beg = rowptr[d], end = rowptr[d + 1];
  const unsigned char* h2l = h2 + lane;
  float den = 0.f, acc = 0.f;

  for (int p0 = beg; p0 < end; p0 += 64) {
    int idx = p0 + lane;
    int se = csr_src[idx < end ? idx : end - 1];
    float v = als[se] + aldd;
    v = fmaxf(v, 0.2f * v);
    float w = (idx < end) ? __expf(v) : 0.f;
    int cnt = min(64, end - p0);
    for (int j0 = 0; j0 < cnt; j0 += 4) {
#pragma unroll
      for (int j = 0; j < 4; ++j) {
        float wj = __shfl(w, j0 + j);
        int sj = __shfl(se, j0 + j);
        float g = __builtin_amdgcn_cvt_f32_fp8(h2l[(size_t)sj * 64], 0);
        den += wj; acc += wj * g;
      }
    }
  }

  float z = acc / (den + 1e-16f) + b2[lane];
  float zm = z;
#pragma unroll
  for (int off = 32; off; off >>= 1) zm = fmaxf(zm, __shfl_xor(zm, off, 64));
  float ex = __expf(z - zm), se2 = ex;
#pragma unroll
  for (int off = 32; off; off >>= 1) se2 += __shfl_xor(se2, off, 64);
  out[(size_t)d * 64 + lane] = z - zm - __logf(se2);
}

// ------------------------------- launch -----------------------------------
extern "C" void kernel_launch(void* const* d_in, const int* in_sizes, int n_in,
                              void* d_out, int out_size, void* d_ws, size_t ws_size,
                              hipStream_t stream) {
  const int N = in_sizes[0] / 256;   // 50000
  const int E = in_sizes[1] / 2;     // 800000
  const int ET = E + N;
  const int CS = (ET + NCHUNK - 1) / NCHUNK;
  const int NB = (N + 1023) / 1024;

  const float* x   = (const float*)d_in[0];
  const int*   ei  = (const int*)d_in[1];
  const float* W1  = (const float*)d_in[2];
  const float* as1 = (const float*)d_in[3];
  const float* ad1 = (const float*)d_in[4];
  const float* b1  = (const float*)d_in[5];
  const float* W2  = (const float*)d_in[6];
  const float* as2 = (const float*)d_in[7];
  const float* ad2 = (const float*)d_in[8];
  const float* b2  = (const float*)d_in[9];
  float* out = (float*)d_out;

  // workspace carve. h2f8 aliases h1f8 (h1 dead after attn1).
  // hist (12.8 MB) aliases helu (hist dead after scatter2; attn1 writes helu).
  char* p = (char*)d_ws;
  unsigned char* h1f8 = (unsigned char*)p; p += (size_t)N * 128;
  unsigned char* h2f8 = h1f8;                      // alias, [N][64]
  unsigned short* helu = (unsigned short*)p; p += (size_t)NCHUNK * N * 4;  // w/ hist
  int* hist = (int*)helu;
  unsigned short* Wt1  = (unsigned short*)p; p += (size_t)128 * 256 * 2;
  unsigned short* Wt2  = (unsigned short*)p; p += (size_t)64 * 128 * 2;
  float* als1 = (float*)p; p += (size_t)N * 8 * 4;
  float* ald1 = (float*)p; p += (size_t)N * 8 * 4;
  float* als2 = (float*)p; p += (size_t)N * 4;
  float* ald2 = (float*)p; p += (size_t)N * 4;
  int* deg     = (int*)p; p += (size_t)N * 4;
  int* rowptr  = (int*)p; p += (size_t)(N + 1) * 4;
  int* bsum    = (int*)p; p += 64 * 4;
  int* csr_src = (int*)p; p += (size_t)ET * 4;

  hist_kernel<<<NCHUNK * NRANGE + CONVB, 512, 0, stream>>>(ei, hist, W1, W2, Wt1, Wt2,
                                                           E, N, ET, CS);
  colscan_kernel<<<(N + 255) / 256, 256, 0, stream>>>(hist, deg, N);
  scan1_kernel<<<NB, 1024, 0, stream>>>(deg, rowptr, bsum, N);
  scan3_kernel<<<(N + 256) / 256, 256, 0, stream>>>(rowptr, bsum, N, ET);
  scatter2_kernel<<<NCHUNK * NRANGE, 512, 0, stream>>>(ei, hist, rowptr, csr_src, E, N, ET, CS);

  gemm1_mfma<<<2 * ((N + 63) / 64), 256, 0, stream>>>(x, Wt1, as1, ad1, h1f8, als1, ald1, N);
  attn1_kernel<<<(N + 3) / 4, 256, 0, stream>>>(h1f8, als1, ald1, b1, rowptr, csr_src, helu, N);

  gemm2_mfma<<<(N + 63) / 64, 256, 0, stream>>>(helu, Wt2, as2, ad2, h2f8, als2, ald2, N);
  attn2_kernel<<<(N + 3) / 4, 256, 0, stream>>>(h2f8, als2, ald2, b2, rowptr, csr_src, out, N);
}